// Round 9
// baseline (725.993 us; speedup 1.0000x reference)
//
#include <hip/hip_runtime.h>
#include <hip/hip_bf16.h>
#include <math.h>

#define Lc 1024
#define Dc 256
#define Bc 32
#define Hc 4
#define Ec 64
#define TOPK 34
#define LEFTc 205

typedef unsigned short u16;
typedef __attribute__((ext_vector_type(8))) short bf16x8;
typedef __attribute__((ext_vector_type(4))) float f32x4;

__device__ __forceinline__ float bf2f(u16 u) {
    return __uint_as_float(((unsigned)u) << 16);
}
__device__ __forceinline__ u16 f2bf(float f) {        // round-to-nearest-even
    unsigned u = __float_as_uint(f);
    u += 0x7FFFu + ((u >> 16) & 1u);
    return (u16)(u >> 16);
}

// ---------------------------------------------------------------------------
// dtype probe: flag=1 means underlying data is fp32.
__global__ void detect_k(const u16* __restrict__ x, int* __restrict__ flag) {
    __shared__ int cnt;
    if (threadIdx.x == 0) cnt = 0;
    __syncthreads();
    int bad = 0;
    for (int i = threadIdx.x; i < 4096; i += 256) {
        float a = fabsf(bf2f(x[i]));
        if (!(a == 0.0f || (a >= 1e-8f && a <= 1e8f))) bad++;
    }
    atomicAdd(&cnt, bad);
    __syncthreads();
    if (threadIdx.x == 0) *flag = (cnt > 512) ? 1 : 0;
}

// One launch ingests all 17 inputs into bf16 scratch.
struct SrcPtrs { const void* p[17]; };
__global__ __launch_bounds__(256) void ingest_all_k(
    SrcPtrs sp, u16* __restrict__ cx, u16* __restrict__ wts, const int* __restrict__ flag)
{
    const long NB = (long)Bc * Lc * Dc;             // 8,388,608
    long i = (long)blockIdx.x * 256 + threadIdx.x;
    const int fp = *flag;
    const void* src; u16* dst; long off;
    if (i < NB) {
        src = sp.p[0]; dst = cx; off = i;
    } else {
        long j = i - NB;
        if (j < 6L * 65536) {                       // Wq,Wk,Wv,Wd,W1,W2
            const int w = (int)(j >> 16); off = j & 65535;
            const int wsidx[6] = {1, 3, 5, 7, 11, 13};
            src = sp.p[wsidx[w]]; dst = wts + (long)w * 65536;
        } else {
            long k2 = j - 6L * 65536;
            if (k2 >= 2560) return;                 // bq,bk,bv,bd,l1g,l1b,b1,b2,l2g,l2b
            const int v = (int)(k2 >> 8); off = k2 & 255;
            const int vsidx[10] = {2, 4, 6, 8, 9, 10, 12, 14, 15, 16};
            src = sp.p[vsidx[v]]; dst = wts + 6L * 65536 + (long)v * 256;
        }
    }
    dst[off] = fp ? f2bf(((const float*)src)[off]) : ((const u16*)src)[off];
}

// ---------------------------------------------------------------------------
// Band-pass kernel h[d] = (1/L)(2*sum_{f=205}^{511} cos(2pi f d/L) + cos(pi d))
// Exact angle reduction (integer mod 1024) + HW cosf: error ~1e-5 << bf16 eps.
__global__ void build_h(float* __restrict__ hf) {
    int d = blockIdx.x * blockDim.x + threadIdx.x;
    if (d >= Lc) return;
    float s = 0.f;
    for (int f = LEFTc; f < 512; ++f) {
        int m = (f * d) & (Lc - 1);
        s += __cosf((float)m * 6.135923151542565e-3f);   // 2pi/1024
    }
    float ny = (d & 1) ? -1.f : 1.f;
    hf[d] = (2.f * s + ny) * (1.f / 1024.f);
}

__global__ void build_G(const float* __restrict__ hf, u16* __restrict__ G) {
    int i = blockIdx.x * 256 + threadIdx.x;
    int t = i >> 10, s = i & (Lc - 1);
    G[i] = f2bf(hf[(t - s) & (Lc - 1)]);
}

// ---------------------------------------------------------------------------
// Transpose (B, L, D) bf16 -> (B, D, L) bf16.
__global__ __launch_bounds__(256) void transpose_k(
    const u16* __restrict__ in, u16* __restrict__ out)
{
    __shared__ u16 t[32][33];
    const int l0 = blockIdx.x * 32, d0 = blockIdx.y * 32, b = blockIdx.z;
    const int tx = threadIdx.x & 31, ty = threadIdx.x >> 5;
    const u16* ib = in + (size_t)b * Lc * Dc;
    #pragma unroll
    for (int i = 0; i < 4; ++i)
        t[ty + i * 8][tx] = ib[(size_t)(l0 + ty + i * 8) * Dc + d0 + tx];
    __syncthreads();
    u16* ob = out + (size_t)b * Dc * Lc;
    #pragma unroll
    for (int i = 0; i < 4; ++i)
        ob[(size_t)(d0 + ty + i * 8) * Lc + l0 + tx] = t[tx][ty + i * 8];
}

// Transpose the six 256x256 weight matrices (contiguous): dst[z][n][k]=src[z][k][n]
__global__ __launch_bounds__(256) void wtrans_k(
    const u16* __restrict__ src, u16* __restrict__ dst)
{
    __shared__ u16 t[32][33];
    const int c0 = blockIdx.x * 32, r0 = blockIdx.y * 32;
    const u16* s = src + (size_t)blockIdx.z * 65536;
    u16* d = dst + (size_t)blockIdx.z * 65536;
    const int tx = threadIdx.x & 31, ty = threadIdx.x >> 5;
    #pragma unroll
    for (int i = 0; i < 4; ++i)
        t[ty + i * 8][tx] = s[(r0 + ty + i * 8) * 256 + c0 + tx];
    __syncthreads();
    #pragma unroll
    for (int i = 0; i < 4; ++i)
        d[(c0 + ty + i * 8) * 256 + r0 + tx] = t[tx][ty + i * 8];
}

// ---------------------------------------------------------------------------
// MFMA GEMM: C[M,N] = A[M,K] @ B[K,N], bf16 in/out, fp32 accum. BT is (N,K).
// Block = 4 waves, 128x64 C tile; wave owns 32 rows x 64 cols.
// BT chunk (64 n x 128 k) staged in LDS, frag-ordered + XOR-swizzled.
// T14 async staging: regs hold next chunk; global latency hides under MFMA.
// EPI: 0=+bias, 1=+bias+bf16 resid, 2=gelu(+bias). ACOMB: A=0.9A+0.1A2.
template <int EPI, bool ACOMB>
__global__ __launch_bounds__(256) void mgemm_k(
    const u16* __restrict__ Abase, const u16* __restrict__ A2base,
    const u16* __restrict__ BTbase, const u16* __restrict__ bias,
    const u16* __restrict__ resid, u16* __restrict__ Cbase,
    int M, int N, int K, long strA, long strBT, long strC)
{
    const int z = blockIdx.z;
    const u16* A  = Abase + (size_t)z * strA;
    const u16* BT = BTbase + (size_t)z * strBT;
    u16* C        = Cbase + (size_t)z * strC;
    const int tid = threadIdx.x;
    const int wave = tid >> 6, lane = tid & 63;
    const int m16 = lane & 15, quad = lane >> 4;
    const int m0 = blockIdx.y * 128 + wave * 32;
    const int n0 = blockIdx.x * 64;

    __shared__ __align__(16) u16 sB[8192];   // 16 KB

    const u16* arow0 = A + (size_t)(m0 + m16) * K + quad * 8;
    const u16* arow1 = arow0 + (size_t)16 * K;
    const u16* a2row0 = ACOMB ? (A2base + (size_t)z * strA + (size_t)(m0 + m16) * K + quad * 8) : nullptr;
    const u16* a2row1 = ACOMB ? (a2row0 + (size_t)16 * K) : nullptr;

    // per-thread staging addresses (fixed across kc)
    const u16* bgp[4];
    u16* bls[4];
    #pragma unroll
    for (int i = 0; i < 4; ++i) {
        const int c = tid + i * 256;
        const int nr = c >> 4, ko = c & 15;
        bgp[i] = BT + (size_t)(n0 + nr) * K + ko * 8;
        bls[i] = sB + ((nr >> 4) * 4 + (ko >> 2)) * 512 + (ko & 3) * 128
                    + (((nr & 15) ^ (ko & 3))) * 8;
    }

    bf16x8 breg[4];
    #pragma unroll
    for (int i = 0; i < 4; ++i) breg[i] = *(const bf16x8*)(bgp[i]);

    f32x4 acc[2][4] = {};

    #pragma unroll 1
    for (int kc = 0; kc < K; kc += 128) {
        #pragma unroll
        for (int i = 0; i < 4; ++i) *(bf16x8*)(bls[i]) = breg[i];
        __syncthreads();
        if (kc + 128 < K) {
            #pragma unroll
            for (int i = 0; i < 4; ++i) breg[i] = *(const bf16x8*)(bgp[i] + kc + 128);
        }
        #pragma unroll
        for (int kf = 0; kf < 4; ++kf) {
            bf16x8 a0 = *(const bf16x8*)(arow0 + kc + kf * 32);
            bf16x8 a1 = *(const bf16x8*)(arow1 + kc + kf * 32);
            if (ACOMB) {
                const bf16x8 x0 = *(const bf16x8*)(a2row0 + kc + kf * 32);
                const bf16x8 x1 = *(const bf16x8*)(a2row1 + kc + kf * 32);
                #pragma unroll
                for (int j = 0; j < 8; ++j) {
                    a0[j] = (short)f2bf(0.9f * bf2f((u16)a0[j]) + 0.1f * bf2f((u16)x0[j]));
                    a1[j] = (short)f2bf(0.9f * bf2f((u16)a1[j]) + 0.1f * bf2f((u16)x1[j]));
                }
            }
            #pragma unroll
            for (int nt = 0; nt < 4; ++nt) {
                const bf16x8 bf = *(const bf16x8*)(sB + (nt * 4 + kf) * 512 + quad * 128
                                                      + ((m16 ^ quad)) * 8);
                acc[0][nt] = __builtin_amdgcn_mfma_f32_16x16x32_bf16(a0, bf, acc[0][nt], 0, 0, 0);
                acc[1][nt] = __builtin_amdgcn_mfma_f32_16x16x32_bf16(a1, bf, acc[1][nt], 0, 0, 0);
            }
        }
        __syncthreads();
    }

    #pragma unroll
    for (int ms = 0; ms < 2; ++ms) {
        #pragma unroll
        for (int nt = 0; nt < 4; ++nt) {
            const int col = n0 + nt * 16 + m16;
            const float bv = bias ? bf2f(bias[col]) : 0.f;
            #pragma unroll
            for (int r = 0; r < 4; ++r) {
                const size_t off = (size_t)(m0 + ms * 16 + quad * 4 + r) * N + col;
                float v = acc[ms][nt][r] + bv;
                if (EPI == 1) v += bf2f(resid[off]);
                if (EPI == 2) v = 0.5f * v * (1.0f + erff(v * 0.70710678118654752f));
                C[off] = f2bf(v);
            }
        }
    }
}

// ---------------------------------------------------------------------------
// corr body (r2-proven structure, unchanged math): exact autocorrelation diag
// sums via full-D MFMA; tau constant per lane -> MFMA-register accumulation.
// JOURNAL (5 attempts): this structure = 108 us standalone. Restructures all
// LOST (reg-prefetch 133, LDS-ring 197, mgemm-clone 202, in-loop LDS-atomic
// fusion 732). Now merged with attn into one launch for latency OVERLAP, not
// restructured.
__device__ __forceinline__ void corr_body(
    const u16* __restrict__ qs, const u16* __restrict__ ks,
    float* __restrict__ mv, const int l, u16* smem)
{
    const int b = ((l & 7) << 2) | ((l >> 3) & 3);  // same b -> same XCD (mod-8 rr)
    const int rest = l >> 5;                        // 0..63
    const int g = rest & 15;                        // shift group: a = g*4 + al
    const int uq = rest >> 4;                       // u quarter
    const int wave = threadIdx.x >> 6, lane = threadIdx.x & 63;
    const int m16 = lane & 15, quad = lane >> 4;
    const size_t base = (size_t)b * Lc * Dc;

    float (*red)[124] = (float (*)[124])smem;       // 4 x 124 floats
    for (int i = threadIdx.x; i < 4 * 124; i += 256) ((float*)red)[i] = 0.f;
    __syncthreads();

    f32x4 acc[4] = {};
    #pragma unroll
    for (int ui = 0; ui < 4; ++ui) {
        const int u = uq * 16 + wave * 4 + ui;
        const u16* qrow = qs + base + (size_t)(u * 16 + m16) * Dc + quad * 8;
        const u16* kr[4];
        #pragma unroll
        for (int al = 0; al < 4; ++al) {
            const int s = (u - g * 4 - al) & 63;
            kr[al] = ks + base + (size_t)(s * 16 + m16) * Dc + quad * 8;
        }
        #pragma unroll
        for (int k0 = 0; k0 < Dc; k0 += 32) {
            const bf16x8 aq = *(const bf16x8*)(qrow + k0);
            #pragma unroll
            for (int al = 0; al < 4; ++al) {
                const bf16x8 bk = *(const bf16x8*)(kr[al] + k0);
                acc[al] = __builtin_amdgcn_mfma_f32_16x16x32_bf16(aq, bk, acc[al], 0, 0, 0);
            }
        }
    }

    #pragma unroll
    for (int al = 0; al < 4; ++al)
        #pragma unroll
        for (int r = 0; r < 4; ++r)
            unsafeAtomicAdd(&red[wave][al * 31 + quad * 4 + r - m16 + 15], acc[al][r]);
    __syncthreads();

    if (threadIdx.x < 124) {
        const int al = threadIdx.x / 31, dd = threadIdx.x % 31;   // d = dd - 15
        const float s = red[0][threadIdx.x] + red[1][threadIdx.x] +
                        red[2][threadIdx.x] + red[3][threadIdx.x];
        unsafeAtomicAdd(&mv[b * Lc + (((g * 4 + al) * 16 + dd - 15) & (Lc - 1))], s);
    }
}

// ---------------------------------------------------------------------------
// attn body: flash MFMA attention, 64 Q rows/block, LDS-staged K/V tiles
// (frag-ordered, XOR-swizzled), per-wave P in LDS (swizzled stores), T14
// async staging. No max-subtraction (|S/8| << 88); O scaled at end.
__device__ __forceinline__ void attn_body(
    const u16* __restrict__ qs, const u16* __restrict__ ks,
    const u16* __restrict__ vsT, u16* __restrict__ ctx,
    const int id, u16* smem)
{
    const int lt = id & 15, h = (id >> 4) & 3, b = id >> 6;

    u16* sK = smem;             // 16 KB: 128 s x 64 e, frag-ordered+swz
    u16* sV = smem + 8192;      // 16 KB: 64 e x 128 s (V^T), frag-ordered+swz
    u16* sP = smem + 16384;     // 16 KB: 4 waves x (16 q x 128 s), swz

    const int tid  = threadIdx.x;
    const int wave = tid >> 6;
    const int lane = tid & 63;
    const int m16  = lane & 15;
    const int quad = lane >> 4;
    const int l0   = lt * 64;
    const size_t base = (size_t)b * Lc * Dc + (size_t)h * Ec;
    const size_t vtbase = ((size_t)b * Dc + (size_t)h * Ec) * Lc;

    const u16* qrow = qs + base + (size_t)(l0 + wave * 16 + m16) * Dc + quad * 8;
    const bf16x8 qa0 = *(const bf16x8*)(qrow);
    const bf16x8 qa1 = *(const bf16x8*)(qrow + 32);

    // per-thread staging addresses (fixed across s0)
    const u16* kgp[4]; const u16* vgp[4];
    u16* kls[4]; u16* vls[4];
    #pragma unroll
    for (int i = 0; i < 4; ++i) {
        const int c = tid + i * 256;
        const int sr = c >> 3, eo = c & 7;
        kgp[i] = ks + base + (size_t)sr * Dc + eo * 8;
        kls[i] = sK + ((sr >> 4) * 2 + (eo >> 2)) * 512 + (eo & 3) * 128
                    + (((sr & 15) ^ (eo & 3))) * 8;
        const int er = c >> 4, so = c & 15;
        vgp[i] = vsT + vtbase + (size_t)er * Lc + so * 8;
        vls[i] = sV + ((er >> 4) * 4 + (so >> 2)) * 512 + (so & 3) * 128
                    + (((er & 15) ^ (so & 3))) * 8;
    }

    bf16x8 kreg[4], vreg[4];
    #pragma unroll
    for (int i = 0; i < 4; ++i) {
        kreg[i] = *(const bf16x8*)(kgp[i]);
        vreg[i] = *(const bf16x8*)(vgp[i]);
    }

    f32x4 o[4] = {};
    float rs[4] = {0.f, 0.f, 0.f, 0.f};

    const int rsw = m16 ^ quad;                       // K/V swizzled frag-row
    const int hrd = ((quad & 1) << 1) | (m16 >> 3);   // P read swizzle
    const int prd = (m16 ^ hrd) * 8;

    #pragma unroll 1
    for (int s0 = 0; s0 < Lc; s0 += 128) {
        // write staged tile (previous PV reads fenced by trailing barrier)
        #pragma unroll
        for (int i = 0; i < 4; ++i) {
            *(bf16x8*)(kls[i]) = kreg[i];
            *(bf16x8*)(vls[i]) = vreg[i];
        }
        __syncthreads();
        // prefetch next tile: latency hides under QK + PV
        if (s0 + 128 < Lc) {
            #pragma unroll
            for (int i = 0; i < 4; ++i) {
                kreg[i] = *(const bf16x8*)(kgp[i] + (size_t)(s0 + 128) * Dc);
                vreg[i] = *(const bf16x8*)(vgp[i] + (s0 + 128));
            }
        }

        // ---- QK + fused exp + rowsum; P -> per-wave LDS (A-frag order, swz)
        #pragma unroll
        for (int st = 0; st < 8; ++st) {
            const bf16x8 kb0 = *(const bf16x8*)(sK + (st * 2 + 0) * 512 + quad * 128 + rsw * 8);
            const bf16x8 kb1 = *(const bf16x8*)(sK + (st * 2 + 1) * 512 + quad * 128 + rsw * 8);
            f32x4 c4 = {0.f, 0.f, 0.f, 0.f};
            c4 = __builtin_amdgcn_mfma_f32_16x16x32_bf16(qa0, kb0, c4, 0, 0, 0);
            c4 = __builtin_amdgcn_mfma_f32_16x16x32_bf16(qa1, kb1, c4, 0, 0, 0);
            const int q2 = ((st & 1) << 1) | (m16 >> 3);
            const int hst = ((q2 & 1) << 1) | (quad >> 1);
            u16* pw = sP + wave * 2048 + (st >> 1) * 512 + q2 * 128 + (m16 & 7);
            #pragma unroll
            for (int r = 0; r < 4; ++r) {
                const float p = __expf(c4[r] * 0.125f);   // scores = S/sqrt(E)
                rs[r] += p;
                pw[(((quad * 4 + r) ^ hst)) * 8] = f2bf(p);
            }
        }
        __syncthreads();

        // ---- PV accumulate (A from sP swizzled, B from sV)
        const bf16x8 a0 = *(const bf16x8*)(sP + wave * 2048 + 0 * 512 + quad * 128 + prd);
        const bf16x8 a1 = *(const bf16x8*)(sP + wave * 2048 + 1 * 512 + quad * 128 + prd);
        const bf16x8 a2 = *(const bf16x8*)(sP + wave * 2048 + 2 * 512 + quad * 128 + prd);
        const bf16x8 a3 = *(const bf16x8*)(sP + wave * 2048 + 3 * 512 + quad * 128 + prd);
        #pragma unroll
        for (int nt = 0; nt < 4; ++nt) {
            o[nt] = __builtin_amdgcn_mfma_f32_16x16x32_bf16(a0, *(const bf16x8*)(sV + (nt * 4 + 0) * 512 + quad * 128 + rsw * 8), o[nt], 0, 0, 0);
            o[nt] = __builtin_amdgcn_mfma_f32_16x16x32_bf16(a1, *(const bf16x8*)(sV + (nt * 4 + 1) * 512 + quad * 128 + rsw * 8), o[nt], 0, 0, 0);
            o[nt] = __builtin_amdgcn_mfma_f32_16x16x32_bf16(a2, *(const bf16x8*)(sV + (nt * 4 + 2) * 512 + quad * 128 + rsw * 8), o[nt], 0, 0, 0);
            o[nt] = __builtin_amdgcn_mfma_f32_16x16x32_bf16(a3, *(const bf16x8*)(sV + (nt * 4 + 3) * 512 + quad * 128 + rsw * 8), o[nt], 0, 0, 0);
        }
        __syncthreads();
    }

    // rowsum reduce across the 16 lanes of each quad group (rows are wave-local)
    #pragma unroll
    for (int off = 1; off < 16; off <<= 1) {
        #pragma unroll
        for (int r = 0; r < 4; ++r) rs[r] += __shfl_xor(rs[r], off);
    }
    #pragma unroll
    for (int nt = 0; nt < 4; ++nt) {
        #pragma unroll
        for (int r = 0; r < 4; ++r)
            ctx[base + (size_t)(l0 + wave * 16 + quad * 4 + r) * Dc + nt * 16 + m16] =
                f2bf(o[nt][r] / rs[r]);
    }
}

// ---------------------------------------------------------------------------
// MERGED corr+attn launch: both are latency-bound with all pipes <30% busy
// (corr: MfmaUtil 6%, occ 29%; attn: MfmaUtil 11%, occ 31%) and fully
// independent (read-only qs/ks; disjoint outputs mv/ctx). One kernel with a
// per-block type branch co-schedules their waves on each CU so corr's
// L2-wait slots are filled by attn's MFMA/VALU work. Blocks interleave in
// groups of 8 (period matches XCD round-robin, so BOTH types cover every
// XCD under either RR or chunked dispatch; corr's id%8 == bid%8 preserves
// its XCD-locality swizzle). LDS = union (attn 48KB dominates; 3 blocks/CU,
// same as before for both).
__global__ __launch_bounds__(256) void corrattn_k(
    const u16* __restrict__ qs, const u16* __restrict__ ks,
    const u16* __restrict__ vsT, u16* __restrict__ ctx, float* __restrict__ mv)
{
    __shared__ __align__(16) u16 smem[24576];   // 48 KB union
    const int bid = blockIdx.x;
    const int group = bid >> 3, lane8 = bid & 7;
    const int id = (group >> 1) * 8 + lane8;    // 0..2047 within each type
    if ((group & 1) == 0)
        corr_body(qs, ks, mv, id, smem);
    else
        attn_body(qs, ks, vsT, ctx, id, smem);
}

// ---------------------------------------------------------------------------
// Top-34 over mean-over-batch of mv (shfl-based), then per-batch softmax weights.
__global__ __launch_bounds__(1024) void topk_k(
    const float* __restrict__ mv, int* __restrict__ idx_g, float* __restrict__ w_g)
{
    __shared__ float wvs[16];
    __shared__ int   wis[16];
    __shared__ int   widx;
    __shared__ int   sidx[TOPK];
    const int tid = threadIdx.x;
    const int lane = tid & 63;
    const int wv_id = tid >> 6;

    float g = 0.f;
    for (int b = 0; b < Bc; ++b) g += mv[b * Lc + tid];

    for (int j = 0; j < TOPK; ++j) {
        float v = g; int ix = tid;
        #pragma unroll
        for (int off = 32; off > 0; off >>= 1) {
            const float ov = __shfl_xor(v, off);
            const int   oi = __shfl_xor(ix, off);
            if (ov > v || (ov == v && oi < ix)) { v = ov; ix = oi; }
        }
        if (lane == 0) { wvs[wv_id] = v; wis[wv_id] = ix; }
        __syncthreads();
        if (tid == 0) {
            float bv = wvs[0]; int bi = wis[0];
            for (int u = 1; u < 16; ++u)
                if (wvs[u] > bv || (wvs[u] == bv && wis[u] < bi)) { bv = wvs[u]; bi = wis[u]; }
            widx = bi; sidx[j] = bi; idx_g[j] = bi;
        }
        __syncthreads();
        if (tid == widx) g = -3e38f;
        __syncthreads();
    }
    if (tid < Bc) {
        float wv[TOPK];
        float mx = -3e38f;
        for (int j = 0; j < TOPK; ++j) {
            wv[j] = mv[tid * Lc + sidx[j]] * (1.0f / (float)Dc);
            mx = fmaxf(mx, wv[j]);
        }
        float sum = 0.f;
        for (int j = 0; j < TOPK; ++j) { wv[j] = expf(wv[j] - mx); sum += wv[j]; }
        for (int j = 0; j < TOPK; ++j) w_g[tid * TOPK + j] = wv[j] / sum;
    }
}

// Time-delay agg: wave per t (64 lanes x ushort4 = 256 cols), 4 t per block.
__global__ __launch_bounds__(256) void agg_k(
    const u16* __restrict__ v, const int* __restrict__ idx,
    const float* __restrict__ w, u16* __restrict__ ct)
{
    const int b = blockIdx.y;
    const int t = blockIdx.x * 4 + (threadIdx.x >> 6);
    const int lane = threadIdx.x & 63;
    __shared__ int   sidx[TOPK];
    __shared__ float sw[TOPK];
    if (threadIdx.x < TOPK) { sidx[threadIdx.x] = idx[threadIdx.x]; sw[threadIdx.x] = w[b * TOPK + threadIdx.x]; }
    __syncthreads();
    const u16* vb = v + (size_t)b * Lc * Dc;
    const int c4 = lane * 4;
    float a0 = 0.f, a1 = 0.f, a2 = 0.f, a3 = 0.f;
    for (int j = 0; j < TOPK; ++j) {
        const float wj = sw[j];
        const ushort4 u = *reinterpret_cast<const ushort4*>(
            vb + (size_t)((t + sidx[j]) & (Lc - 1)) * Dc + c4);
        a0 += wj * bf2f(u.x); a1 += wj * bf2f(u.y);
        a2 += wj * bf2f(u.z); a3 += wj * bf2f(u.w);
    }
    ushort4 o; o.x = f2bf(a0); o.y = f2bf(a1); o.z = f2bf(a2); o.w = f2bf(a3);
    *reinterpret_cast<ushort4*>(ct + (size_t)b * Lc * Dc + (size_t)t * Dc + c4) = o;
}

// ---------------------------------------------------------------------------
// LayerNorm: wave per row (64 lanes x 4 elems), shfl reduce, no barriers.
template <bool FINAL>
__global__ __launch_bounds__(256) void ln_k(
    const u16* __restrict__ in, const u16* __restrict__ g,
    const u16* __restrict__ be, void* __restrict__ out, const int* __restrict__ flag)
{
    const int wave = threadIdx.x >> 6, lane = threadIdx.x & 63;
    const int row = blockIdx.x * 4 + wave;
    const int c4 = lane * 4;
    const ushort4 u = *reinterpret_cast<const ushort4*>(in + (size_t)row * Dc + c4);
    float x[4] = {bf2f(u.x), bf2f(u.y), bf2f(u.z), bf2f(u.w)};
    float sm = x[0] + x[1] + x[2] + x[3];
    float sq = x[0]*x[0] + x[1]*x[1] + x[2]*x[2] + x[3]*x[3];
    #pragma unroll
    for (int off = 1; off < 64; off <<= 1) {
        sm += __shfl_xor(sm, off);
        sq += __shfl_xor(sq, off);
    }
    const float mean = sm * (1.f / 256.f);
    const float var = sq * (1.f / 256.f) - mean * mean;
    const float rstd = __frsqrt_rn(var + 1e-8f);
    const ushort4 gg = *reinterpret_cast<const ushort4*>(g + c4);
    const ushort4 bb = *reinterpret_cast<const ushort4*>(be + c4);
    float y[4];
    y[0] = (x[0] - mean) * rstd * bf2f(gg.x) + bf2f(bb.x);
    y[1] = (x[1] - mean) * rstd * bf2f(gg.y) + bf2f(bb.y);
    y[2] = (x[2] - mean) * rstd * bf2f(gg.z) + bf2f(bb.z);
    y[3] = (x[3] - mean) * rstd * bf2f(gg.w) + bf2f(bb.w);
    if (FINAL && *flag) {
        float4 o = make_float4(y[0], y[1], y[2], y[3]);
        *reinterpret_cast<float4*>((float*)out + (size_t)row * Dc + c4) = o;
    } else {
        ushort4 o; o.x = f2bf(y[0]); o.y = f2bf(y[1]); o.z = f2bf(y[2]); o.w = f2bf(y[3]);
        *reinterpret_cast<ushort4*>((u16*)out + (size_t)row * Dc + c4) = o;
    }
}

// ---------------------------------------------------------------------------
extern "C" void kernel_launch(void* const* d_in, const int* in_sizes, int n_in,
                              void* d_out, int out_size, void* d_ws, size_t ws_size,
                              hipStream_t stream)
{
    (void)in_sizes; (void)n_in; (void)out_size; (void)ws_size;

    const size_t BLD = (size_t)Bc * Lc * Dc;        // 8,388,608 elements
    const size_t SLOT = BLD * 2;                    // bf16 slot bytes: 16 MiB
    const long LD = (long)(Lc * Dc);
    char* ws = (char*)d_ws;
    u16* b0 = (u16*)(ws + 0 * SLOT);
    u16* b1 = (u16*)(ws + 1 * SLOT);
    u16* b2 = (u16*)(ws + 2 * SLOT);
    u16* b3 = (u16*)(ws + 3 * SLOT);
    u16* cx = (u16*)(ws + 4 * SLOT);                // converted x
    u16* G  = (u16*)(ws + 5 * SLOT);                // L*L bf16 = 2 MiB
    char* tail = ws + 5 * SLOT + (size_t)Lc * Lc * 2;
    u16* wts  = (u16*)tail;                         // 6*65536 + 10*256
    u16* wtsT = wts + 6 * 65536 + 10 * 256;         // 6*65536 transposed weights
    char* tail2 = (char*)(wtsT + 6 * 65536);
    float* hf  = (float*)(tail2 + 512);
    float* mv  = hf + Lc;
    int*   idx = (int*)(mv + Bc * Lc);
    float* wsm = (float*)(idx + 64);
    int*   flag = (int*)(wsm + Bc * TOPK);

    u16* vecs = wts + 6 * 65536;
    u16* cbv = vecs + 2 * 256;  u16* cbd = vecs + 3 * 256;
    u16* l1g = vecs + 4 * 256;  u16* l1b = vecs + 5 * 256;
    u16* cb1 = vecs + 6 * 256;  u16* cb2 = vecs + 7 * 256;
    u16* l2g = vecs + 8 * 256;  u16* l2b = vecs + 9 * 256;
    u16* wvT = wtsT + 2 * 65536;
    u16* wdT = wtsT + 3 * 65536; u16* w1T = wtsT + 4 * 65536; u16* w2T = wtsT + 5 * 65536;

    // 0. dtype detection + single-launch ingest to bf16 scratch
    detect_k<<<dim3(1), 256, 0, stream>>>((const u16*)d_in[0], flag);
    SrcPtrs sp;
    for (int i = 0; i < 17; ++i) sp.p[i] = d_in[i];
    ingest_all_k<<<dim3(34314), 256, 0, stream>>>(sp, cx, wts, flag);
    wtrans_k<<<dim3(8, 8, 6), 256, 0, stream>>>(wts, wtsT);

    // 1. filter kernel + circulant (bf16)
    build_h<<<dim3(4), 256, 0, stream>>>(hf);
    build_G<<<dim3((Lc * Lc) / 256), 256, 0, stream>>>(hf, G);

    // 2. cxT (b1), then Xf = G @ x (b0). Filtering commutes with projections;
    //    filtered biases vanish (DC bin masked).
    transpose_k<<<dim3(32, 8, 32), 256, 0, stream>>>(cx, b1);
    mgemm_k<0, false><<<dim3(4, 8, 32), 256, 0, stream>>>(
        G, nullptr, b1, nullptr, nullptr, b0, Lc, Dc, Lc, 0, LD, LD);

    // 3. qs/ks/vs = Xf @ {Wq,Wk,Wv} in ONE launch (z=3: contiguous weights/slots)
    mgemm_k<0, false><<<dim3(4, 256, 3), 256, 0, stream>>>(
        b0, nullptr, wtsT, nullptr, nullptr, b1, Bc * Lc, Dc, Dc, 0, 65536, (long)BLD);

    // 4. vsT (b0; Xf dead), then MERGED corr+attn (corr -> mv, ctx -> b3):
    //    two latency-bound kernels co-scheduled in one grid.
    hipMemsetAsync(mv, 0, (size_t)Bc * Lc * 4, stream);
    transpose_k<<<dim3(32, 8, 32), 256, 0, stream>>>(b3, b0);
    corrattn_k<<<dim3(4096), 256, 0, stream>>>(b1, b2, b0, b3, mv);

    // 5. top-k + per-batch softmax weights
    topk_k<<<dim3(1), 1024, 0, stream>>>(mv, idx, wsm);

    // 6. v = x @ Wv + bv (unfiltered; qs dead -> b1), time-delay agg -> b2
    const dim3 gProj(4, 256, 1);
    mgemm_k<0, false><<<gProj, 256, 0, stream>>>(cx, nullptr, wvT, cbv, nullptr, b1, Bc * Lc, Dc, Dc, 0, 0, 0);
    agg_k<<<dim3(256, 32), 256, 0, stream>>>(b1, idx, wsm, b2);

    // 7. d = (0.9*ct + 0.1*ctx) @ Wd + bd + x  -> b0 (vsT dead)
    mgemm_k<1, true><<<gProj, 256, 0, stream>>>(b2, b3, wdT, cbd, cx, b0, Bc * Lc, Dc, Dc, 0, 0, 0);

    // 8. LN1 -> h (b1)
    ln_k<false><<<dim3(8192), 256, 0, stream>>>(b0, l1g, l1b, b1, flag);

    // 9. FFN up + gelu -> b2; FFN down + h residual -> b3
    mgemm_k<2, false><<<gProj, 256, 0, stream>>>(b1, nullptr, w1T, cb1, nullptr, b2, Bc * Lc, Dc, Dc, 0, 0, 0);
    mgemm_k<1, false><<<gProj, 256, 0, stream>>>(b2, nullptr, w2T, cb2, b1, b3, Bc * Lc, Dc, Dc, 0, 0, 0);

    // 10. LN2 -> out (dtype per flag)
    ln_k<true><<<dim3(8192), 256, 0, stream>>>(b3, l2g, l2b, d_out, flag);
}

// Round 10
// 618.319 us; speedup vs baseline: 1.1741x; 1.1741x over previous
//
#include <hip/hip_runtime.h>
#include <hip/hip_bf16.h>
#include <math.h>

#define Lc 1024
#define Dc 256
#define Bc 32
#define Hc 4
#define Ec 64
#define TOPK 34
#define LEFTc 205

typedef unsigned short u16;
typedef __attribute__((ext_vector_type(8))) short bf16x8;
typedef __attribute__((ext_vector_type(4))) float f32x4;

__device__ __forceinline__ float bf2f(u16 u) {
    return __uint_as_float(((unsigned)u) << 16);
}
__device__ __forceinline__ u16 f2bf(float f) {        // round-to-nearest-even
    unsigned u = __float_as_uint(f);
    u += 0x7FFFu + ((u >> 16) & 1u);
    return (u16)(u >> 16);
}

// ---------------------------------------------------------------------------
// dtype probe: flag=1 means underlying data is fp32.
__global__ void detect_k(const u16* __restrict__ x, int* __restrict__ flag) {
    __shared__ int cnt;
    if (threadIdx.x == 0) cnt = 0;
    __syncthreads();
    int bad = 0;
    for (int i = threadIdx.x; i < 4096; i += 256) {
        float a = fabsf(bf2f(x[i]));
        if (!(a == 0.0f || (a >= 1e-8f && a <= 1e8f))) bad++;
    }
    atomicAdd(&cnt, bad);
    __syncthreads();
    if (threadIdx.x == 0) *flag = (cnt > 512) ? 1 : 0;
}

// One launch ingests all 17 inputs into bf16 scratch.
struct SrcPtrs { const void* p[17]; };
__global__ __launch_bounds__(256) void ingest_all_k(
    SrcPtrs sp, u16* __restrict__ cx, u16* __restrict__ wts, const int* __restrict__ flag)
{
    const long NB = (long)Bc * Lc * Dc;             // 8,388,608
    long i = (long)blockIdx.x * 256 + threadIdx.x;
    const int fp = *flag;
    const void* src; u16* dst; long off;
    if (i < NB) {
        src = sp.p[0]; dst = cx; off = i;
    } else {
        long j = i - NB;
        if (j < 6L * 65536) {                       // Wq,Wk,Wv,Wd,W1,W2
            const int w = (int)(j >> 16); off = j & 65535;
            const int wsidx[6] = {1, 3, 5, 7, 11, 13};
            src = sp.p[wsidx[w]]; dst = wts + (long)w * 65536;
        } else {
            long k2 = j - 6L * 65536;
            if (k2 >= 2560) return;                 // bq,bk,bv,bd,l1g,l1b,b1,b2,l2g,l2b
            const int v = (int)(k2 >> 8); off = k2 & 255;
            const int vsidx[10] = {2, 4, 6, 8, 9, 10, 12, 14, 15, 16};
            src = sp.p[vsidx[v]]; dst = wts + 6L * 65536 + (long)v * 256;
        }
    }
    dst[off] = fp ? f2bf(((const float*)src)[off]) : ((const u16*)src)[off];
}

// ---------------------------------------------------------------------------
// Band-pass kernel h[d] = (1/L)(2*sum_{f=205}^{511} cos(2pi f d/L) + cos(pi d))
// Exact angle reduction (integer mod 1024) + HW cosf: error ~1e-5 << bf16 eps.
__global__ void build_h(float* __restrict__ hf) {
    int d = blockIdx.x * blockDim.x + threadIdx.x;
    if (d >= Lc) return;
    float s = 0.f;
    for (int f = LEFTc; f < 512; ++f) {
        int m = (f * d) & (Lc - 1);
        s += __cosf((float)m * 6.135923151542565e-3f);   // 2pi/1024
    }
    float ny = (d & 1) ? -1.f : 1.f;
    hf[d] = (2.f * s + ny) * (1.f / 1024.f);
}

__global__ void build_G(const float* __restrict__ hf, u16* __restrict__ G) {
    int i = blockIdx.x * 256 + threadIdx.x;
    int t = i >> 10, s = i & (Lc - 1);
    G[i] = f2bf(hf[(t - s) & (Lc - 1)]);
}

// ---------------------------------------------------------------------------
// Transpose (B, L, D) bf16 -> (B, D, L) bf16.
__global__ __launch_bounds__(256) void transpose_k(
    const u16* __restrict__ in, u16* __restrict__ out)
{
    __shared__ u16 t[32][33];
    const int l0 = blockIdx.x * 32, d0 = blockIdx.y * 32, b = blockIdx.z;
    const int tx = threadIdx.x & 31, ty = threadIdx.x >> 5;
    const u16* ib = in + (size_t)b * Lc * Dc;
    #pragma unroll
    for (int i = 0; i < 4; ++i)
        t[ty + i * 8][tx] = ib[(size_t)(l0 + ty + i * 8) * Dc + d0 + tx];
    __syncthreads();
    u16* ob = out + (size_t)b * Dc * Lc;
    #pragma unroll
    for (int i = 0; i < 4; ++i)
        ob[(size_t)(d0 + ty + i * 8) * Lc + l0 + tx] = t[tx][ty + i * 8];
}

// Transpose the six 256x256 weight matrices (contiguous): dst[z][n][k]=src[z][k][n]
__global__ __launch_bounds__(256) void wtrans_k(
    const u16* __restrict__ src, u16* __restrict__ dst)
{
    __shared__ u16 t[32][33];
    const int c0 = blockIdx.x * 32, r0 = blockIdx.y * 32;
    const u16* s = src + (size_t)blockIdx.z * 65536;
    u16* d = dst + (size_t)blockIdx.z * 65536;
    const int tx = threadIdx.x & 31, ty = threadIdx.x >> 5;
    #pragma unroll
    for (int i = 0; i < 4; ++i)
        t[ty + i * 8][tx] = s[(r0 + ty + i * 8) * 256 + c0 + tx];
    __syncthreads();
    #pragma unroll
    for (int i = 0; i < 4; ++i)
        d[(c0 + ty + i * 8) * 256 + r0 + tx] = t[tx][ty + i * 8];
}

// ---------------------------------------------------------------------------
// MFMA GEMM: C[M,N] = A[M,K] @ B[K,N], bf16 in/out, fp32 accum. BT is (N,K).
// Block = 4 waves, 128x64 C tile; wave owns 32 rows x 64 cols.
// BT chunk (64 n x 128 k) staged in LDS, frag-ordered + XOR-swizzled.
// T14 async staging: regs hold next chunk; global latency hides under MFMA.
// EPI: 0=+bias, 1=+bias+bf16 resid, 2=gelu(+bias). ACOMB: A=0.9A+0.1A2.
template <int EPI, bool ACOMB>
__global__ __launch_bounds__(256) void mgemm_k(
    const u16* __restrict__ Abase, const u16* __restrict__ A2base,
    const u16* __restrict__ BTbase, const u16* __restrict__ bias,
    const u16* __restrict__ resid, u16* __restrict__ Cbase,
    int M, int N, int K, long strA, long strBT, long strC)
{
    const int z = blockIdx.z;
    const u16* A  = Abase + (size_t)z * strA;
    const u16* BT = BTbase + (size_t)z * strBT;
    u16* C        = Cbase + (size_t)z * strC;
    const int tid = threadIdx.x;
    const int wave = tid >> 6, lane = tid & 63;
    const int m16 = lane & 15, quad = lane >> 4;
    const int m0 = blockIdx.y * 128 + wave * 32;
    const int n0 = blockIdx.x * 64;

    __shared__ __align__(16) u16 sB[8192];   // 16 KB

    const u16* arow0 = A + (size_t)(m0 + m16) * K + quad * 8;
    const u16* arow1 = arow0 + (size_t)16 * K;
    const u16* a2row0 = ACOMB ? (A2base + (size_t)z * strA + (size_t)(m0 + m16) * K + quad * 8) : nullptr;
    const u16* a2row1 = ACOMB ? (a2row0 + (size_t)16 * K) : nullptr;

    // per-thread staging addresses (fixed across kc)
    const u16* bgp[4];
    u16* bls[4];
    #pragma unroll
    for (int i = 0; i < 4; ++i) {
        const int c = tid + i * 256;
        const int nr = c >> 4, ko = c & 15;
        bgp[i] = BT + (size_t)(n0 + nr) * K + ko * 8;
        bls[i] = sB + ((nr >> 4) * 4 + (ko >> 2)) * 512 + (ko & 3) * 128
                    + (((nr & 15) ^ (ko & 3))) * 8;
    }

    bf16x8 breg[4];
    #pragma unroll
    for (int i = 0; i < 4; ++i) breg[i] = *(const bf16x8*)(bgp[i]);

    f32x4 acc[2][4] = {};

    #pragma unroll 1
    for (int kc = 0; kc < K; kc += 128) {
        #pragma unroll
        for (int i = 0; i < 4; ++i) *(bf16x8*)(bls[i]) = breg[i];
        __syncthreads();
        if (kc + 128 < K) {
            #pragma unroll
            for (int i = 0; i < 4; ++i) breg[i] = *(const bf16x8*)(bgp[i] + kc + 128);
        }
        #pragma unroll
        for (int kf = 0; kf < 4; ++kf) {
            bf16x8 a0 = *(const bf16x8*)(arow0 + kc + kf * 32);
            bf16x8 a1 = *(const bf16x8*)(arow1 + kc + kf * 32);
            if (ACOMB) {
                const bf16x8 x0 = *(const bf16x8*)(a2row0 + kc + kf * 32);
                const bf16x8 x1 = *(const bf16x8*)(a2row1 + kc + kf * 32);
                #pragma unroll
                for (int j = 0; j < 8; ++j) {
                    a0[j] = (short)f2bf(0.9f * bf2f((u16)a0[j]) + 0.1f * bf2f((u16)x0[j]));
                    a1[j] = (short)f2bf(0.9f * bf2f((u16)a1[j]) + 0.1f * bf2f((u16)x1[j]));
                }
            }
            #pragma unroll
            for (int nt = 0; nt < 4; ++nt) {
                const bf16x8 bf = *(const bf16x8*)(sB + (nt * 4 + kf) * 512 + quad * 128
                                                      + ((m16 ^ quad)) * 8);
                acc[0][nt] = __builtin_amdgcn_mfma_f32_16x16x32_bf16(a0, bf, acc[0][nt], 0, 0, 0);
                acc[1][nt] = __builtin_amdgcn_mfma_f32_16x16x32_bf16(a1, bf, acc[1][nt], 0, 0, 0);
            }
        }
        __syncthreads();
    }

    #pragma unroll
    for (int ms = 0; ms < 2; ++ms) {
        #pragma unroll
        for (int nt = 0; nt < 4; ++nt) {
            const int col = n0 + nt * 16 + m16;
            const float bv = bias ? bf2f(bias[col]) : 0.f;
            #pragma unroll
            for (int r = 0; r < 4; ++r) {
                const size_t off = (size_t)(m0 + ms * 16 + quad * 4 + r) * N + col;
                float v = acc[ms][nt][r] + bv;
                if (EPI == 1) v += bf2f(resid[off]);
                if (EPI == 2) v = 0.5f * v * (1.0f + erff(v * 0.70710678118654752f));
                C[off] = f2bf(v);
            }
        }
    }
}

// ---------------------------------------------------------------------------
// Exact autocorrelation diag sums via full-D MFMA (heads are disjoint column
// blocks, so full-D dot = sum over heads). 2048 blocks: block = (u-quarter,
// shift group of 4, batch b XCD-swizzled). tau constant per lane -> MFMA-
// register accumulation. The 32-step loop is fully unrolled with 160
// independent global loads; __launch_bounds__(256, 1) lifts the register
// budget (default scheduling kept VGPR=76 ~ only 5 loads in flight) so the
// scheduler can hoist loads and overlap the ~300cy L2/L3 latency.
// JOURNAL (6 attempts): this structure = 108 us standalone. Restructures all
// LOST: 8-shift reg-prefetch 133 (compiler folds reg dbuf); LDS-ring 197
// (73KB LDS -> 2 blocks/CU); mgemm-clone 202 (XCD fetch amplification);
// in-loop LDS-atomic fusion 732 (LDS pipe serialization); corr+attn merged
// launch 302 vs 213 serial (LDS union kills corr TLP + L2 thrash). Do not
// restructure; only per-wave depth/hints.
__global__ __launch_bounds__(256, 1) void corr_k(
    const u16* __restrict__ qs, const u16* __restrict__ ks, float* __restrict__ mv)
{
    const int l = blockIdx.x;                       // 0..2047
    const int b = ((l & 7) << 2) | ((l >> 3) & 3);  // same b -> same XCD (mod-8 rr)
    const int rest = l >> 5;                        // 0..63
    const int g = rest & 15;                        // shift group: a = g*4 + al
    const int uq = rest >> 4;                       // u quarter
    const int wave = threadIdx.x >> 6, lane = threadIdx.x & 63;
    const int m16 = lane & 15, quad = lane >> 4;
    const size_t base = (size_t)b * Lc * Dc;

    __shared__ float red[4][124];                   // [wave][al*31 + d+15]
    for (int i = threadIdx.x; i < 4 * 124; i += 256) ((float*)red)[i] = 0.f;
    __syncthreads();

    f32x4 acc[4] = {};
    #pragma unroll
    for (int ui = 0; ui < 4; ++ui) {
        const int u = uq * 16 + wave * 4 + ui;
        const u16* qrow = qs + base + (size_t)(u * 16 + m16) * Dc + quad * 8;
        const u16* kr[4];
        #pragma unroll
        for (int al = 0; al < 4; ++al) {
            const int s = (u - g * 4 - al) & 63;
            kr[al] = ks + base + (size_t)(s * 16 + m16) * Dc + quad * 8;
        }
        #pragma unroll
        for (int k0 = 0; k0 < Dc; k0 += 32) {
            const bf16x8 aq = *(const bf16x8*)(qrow + k0);
            #pragma unroll
            for (int al = 0; al < 4; ++al) {
                const bf16x8 bk = *(const bf16x8*)(kr[al] + k0);
                acc[al] = __builtin_amdgcn_mfma_f32_16x16x32_bf16(aq, bk, acc[al], 0, 0, 0);
            }
        }
    }

    #pragma unroll
    for (int al = 0; al < 4; ++al)
        #pragma unroll
        for (int r = 0; r < 4; ++r)
            unsafeAtomicAdd(&red[wave][al * 31 + quad * 4 + r - m16 + 15], acc[al][r]);
    __syncthreads();

    if (threadIdx.x < 124) {
        const int al = threadIdx.x / 31, dd = threadIdx.x % 31;   // d = dd - 15
        const float s = red[0][threadIdx.x] + red[1][threadIdx.x] +
                        red[2][threadIdx.x] + red[3][threadIdx.x];
        unsafeAtomicAdd(&mv[b * Lc + (((g * 4 + al) * 16 + dd - 15) & (Lc - 1))], s);
    }
}

// ---------------------------------------------------------------------------
// Flash MFMA attention, 64 Q rows/block, LDS-staged K/V tiles (frag-ordered,
// XOR-swizzled), per-wave P in LDS (XOR-swizzled stores -> conflict-free).
// T14 async staging: next K/V tile loaded to regs during QK+PV compute.
// No max-subtraction (|S/8| << 88); O scaled at end. exp folded to a single
// exp2 (VALU is the busier pipe: 29% vs MFMA 11%).
// NOTE: corr fusion (r3/r4) and corr merge (r9) both LOSE -- keep separate.
__global__ __launch_bounds__(256) void attn_k(
    const u16* __restrict__ qs, const u16* __restrict__ ks,
    const u16* __restrict__ vsT, u16* __restrict__ ctx)
{
    const int lt = blockIdx.x, h = blockIdx.y, b = blockIdx.z;

    __shared__ __align__(16) u16 sK[8192];   // 128 s x 64 e, frag-ordered+swz
    __shared__ __align__(16) u16 sV[8192];   // 64 e x 128 s (V^T), frag-ordered+swz
    __shared__ __align__(16) u16 sP[8192];   // 4 waves x (16 q x 128 s), swz

    const int tid  = threadIdx.x;
    const int wave = tid >> 6;
    const int lane = tid & 63;
    const int m16  = lane & 15;
    const int quad = lane >> 4;
    const int l0   = lt * 64;
    const size_t base = (size_t)b * Lc * Dc + (size_t)h * Ec;
    const size_t vtbase = ((size_t)b * Dc + (size_t)h * Ec) * Lc;

    const u16* qrow = qs + base + (size_t)(l0 + wave * 16 + m16) * Dc + quad * 8;
    const bf16x8 qa0 = *(const bf16x8*)(qrow);
    const bf16x8 qa1 = *(const bf16x8*)(qrow + 32);

    // per-thread staging addresses (fixed across s0)
    const u16* kgp[4]; const u16* vgp[4];
    u16* kls[4]; u16* vls[4];
    #pragma unroll
    for (int i = 0; i < 4; ++i) {
        const int c = tid + i * 256;
        const int sr = c >> 3, eo = c & 7;
        kgp[i] = ks + base + (size_t)sr * Dc + eo * 8;
        kls[i] = sK + ((sr >> 4) * 2 + (eo >> 2)) * 512 + (eo & 3) * 128
                    + (((sr & 15) ^ (eo & 3))) * 8;
        const int er = c >> 4, so = c & 15;
        vgp[i] = vsT + vtbase + (size_t)er * Lc + so * 8;
        vls[i] = sV + ((er >> 4) * 4 + (so >> 2)) * 512 + (so & 3) * 128
                    + (((er & 15) ^ (so & 3))) * 8;
    }

    bf16x8 kreg[4], vreg[4];
    #pragma unroll
    for (int i = 0; i < 4; ++i) {
        kreg[i] = *(const bf16x8*)(kgp[i]);
        vreg[i] = *(const bf16x8*)(vgp[i]);
    }

    f32x4 o[4] = {};
    float rs[4] = {0.f, 0.f, 0.f, 0.f};

    const int rsw = m16 ^ quad;                       // K/V swizzled frag-row
    const int hrd = ((quad & 1) << 1) | (m16 >> 3);   // P read swizzle
    const int prd = (m16 ^ hrd) * 8;

    #pragma unroll 1
    for (int s0 = 0; s0 < Lc; s0 += 128) {
        // write staged tile (previous PV reads fenced by trailing barrier)
        #pragma unroll
        for (int i = 0; i < 4; ++i) {
            *(bf16x8*)(kls[i]) = kreg[i];
            *(bf16x8*)(vls[i]) = vreg[i];
        }
        __syncthreads();
        // prefetch next tile: latency hides under QK + PV
        if (s0 + 128 < Lc) {
            #pragma unroll
            for (int i = 0; i < 4; ++i) {
                kreg[i] = *(const bf16x8*)(kgp[i] + (size_t)(s0 + 128) * Dc);
                vreg[i] = *(const bf16x8*)(vgp[i] + (s0 + 128));
            }
        }

        // ---- QK + fused exp + rowsum; P -> per-wave LDS (A-frag order, swz)
        #pragma unroll
        for (int st = 0; st < 8; ++st) {
            const bf16x8 kb0 = *(const bf16x8*)(sK + (st * 2 + 0) * 512 + quad * 128 + rsw * 8);
            const bf16x8 kb1 = *(const bf16x8*)(sK + (st * 2 + 1) * 512 + quad * 128 + rsw * 8);
            f32x4 c4 = {0.f, 0.f, 0.f, 0.f};
            c4 = __builtin_amdgcn_mfma_f32_16x16x32_bf16(qa0, kb0, c4, 0, 0, 0);
            c4 = __builtin_amdgcn_mfma_f32_16x16x32_bf16(qa1, kb1, c4, 0, 0, 0);
            const int q2 = ((st & 1) << 1) | (m16 >> 3);
            const int hst = ((q2 & 1) << 1) | (quad >> 1);
            u16* pw = sP + wave * 2048 + (st >> 1) * 512 + q2 * 128 + (m16 & 7);
            #pragma unroll
            for (int r = 0; r < 4; ++r) {
                // exp(S/8) = exp2(S * 0.125*log2(e)) -- one mul + one v_exp
                const float p = __builtin_amdgcn_exp2f(c4[r] * 0.1803368801111204f);
                rs[r] += p;
                pw[(((quad * 4 + r) ^ hst)) * 8] = f2bf(p);
            }
        }
        __syncthreads();

        // ---- PV accumulate (A from sP swizzled, B from sV)
        const bf16x8 a0 = *(const bf16x8*)(sP + wave * 2048 + 0 * 512 + quad * 128 + prd);
        const bf16x8 a1 = *(const bf16x8*)(sP + wave * 2048 + 1 * 512 + quad * 128 + prd);
        const bf16x8 a2 = *(const bf16x8*)(sP + wave * 2048 + 2 * 512 + quad * 128 + prd);
        const bf16x8 a3 = *(const bf16x8*)(sP + wave * 2048 + 3 * 512 + quad * 128 + prd);
        #pragma unroll
        for (int nt = 0; nt < 4; ++nt) {
            o[nt] = __builtin_amdgcn_mfma_f32_16x16x32_bf16(a0, *(const bf16x8*)(sV + (nt * 4 + 0) * 512 + quad * 128 + rsw * 8), o[nt], 0, 0, 0);
            o[nt] = __builtin_amdgcn_mfma_f32_16x16x32_bf16(a1, *(const bf16x8*)(sV + (nt * 4 + 1) * 512 + quad * 128 + rsw * 8), o[nt], 0, 0, 0);
            o[nt] = __builtin_amdgcn_mfma_f32_16x16x32_bf16(a2, *(const bf16x8*)(sV + (nt * 4 + 2) * 512 + quad * 128 + rsw * 8), o[nt], 0, 0, 0);
            o[nt] = __builtin_amdgcn_mfma_f32_16x16x32_bf16(a3, *(const bf16x8*)(sV + (nt * 4 + 3) * 512 + quad * 128 + rsw * 8), o[nt], 0, 0, 0);
        }
        __syncthreads();
    }

    // rowsum reduce across the 16 lanes of each quad group (rows are wave-local)
    #pragma unroll
    for (int off = 1; off < 16; off <<= 1) {
        #pragma unroll
        for (int r = 0; r < 4; ++r) rs[r] += __shfl_xor(rs[r], off);
    }
    #pragma unroll
    for (int nt = 0; nt < 4; ++nt) {
        #pragma unroll
        for (int r = 0; r < 4; ++r)
            ctx[base + (size_t)(l0 + wave * 16 + quad * 4 + r) * Dc + nt * 16 + m16] =
                f2bf(o[nt][r] / rs[r]);
    }
}

// ---------------------------------------------------------------------------
// Top-34 over mean-over-batch of mv (shfl-based), then per-batch softmax weights.
__global__ __launch_bounds__(1024) void topk_k(
    const float* __restrict__ mv, int* __restrict__ idx_g, float* __restrict__ w_g)
{
    __shared__ float wvs[16];
    __shared__ int   wis[16];
    __shared__ int   widx;
    __shared__ int   sidx[TOPK];
    const int tid = threadIdx.x;
    const int lane = tid & 63;
    const int wv_id = tid >> 6;

    float g = 0.f;
    for (int b = 0; b < Bc; ++b) g += mv[b * Lc + tid];

    for (int j = 0; j < TOPK; ++j) {
        float v = g; int ix = tid;
        #pragma unroll
        for (int off = 32; off > 0; off >>= 1) {
            const float ov = __shfl_xor(v, off);
            const int   oi = __shfl_xor(ix, off);
            if (ov > v || (ov == v && oi < ix)) { v = ov; ix = oi; }
        }
        if (lane == 0) { wvs[wv_id] = v; wis[wv_id] = ix; }
        __syncthreads();
        if (tid == 0) {
            float bv = wvs[0]; int bi = wis[0];
            for (int u = 1; u < 16; ++u)
                if (wvs[u] > bv || (wvs[u] == bv && wis[u] < bi)) { bv = wvs[u]; bi = wis[u]; }
            widx = bi; sidx[j] = bi; idx_g[j] = bi;
        }
        __syncthreads();
        if (tid == widx) g = -3e38f;
        __syncthreads();
    }
    if (tid < Bc) {
        float wv[TOPK];
        float mx = -3e38f;
        for (int j = 0; j < TOPK; ++j) {
            wv[j] = mv[tid * Lc + sidx[j]] * (1.0f / (float)Dc);
            mx = fmaxf(mx, wv[j]);
        }
        float sum = 0.f;
        for (int j = 0; j < TOPK; ++j) { wv[j] = expf(wv[j] - mx); sum += wv[j]; }
        for (int j = 0; j < TOPK; ++j) w_g[tid * TOPK + j] = wv[j] / sum;
    }
}

// Time-delay agg: wave per t (64 lanes x ushort4 = 256 cols), 4 t per block.
__global__ __launch_bounds__(256) void agg_k(
    const u16* __restrict__ v, const int* __restrict__ idx,
    const float* __restrict__ w, u16* __restrict__ ct)
{
    const int b = blockIdx.y;
    const int t = blockIdx.x * 4 + (threadIdx.x >> 6);
    const int lane = threadIdx.x & 63;
    __shared__ int   sidx[TOPK];
    __shared__ float sw[TOPK];
    if (threadIdx.x < TOPK) { sidx[threadIdx.x] = idx[threadIdx.x]; sw[threadIdx.x] = w[b * TOPK + threadIdx.x]; }
    __syncthreads();
    const u16* vb = v + (size_t)b * Lc * Dc;
    const int c4 = lane * 4;
    float a0 = 0.f, a1 = 0.f, a2 = 0.f, a3 = 0.f;
    for (int j = 0; j < TOPK; ++j) {
        const float wj = sw[j];
        const ushort4 u = *reinterpret_cast<const ushort4*>(
            vb + (size_t)((t + sidx[j]) & (Lc - 1)) * Dc + c4);
        a0 += wj * bf2f(u.x); a1 += wj * bf2f(u.y);
        a2 += wj * bf2f(u.z); a3 += wj * bf2f(u.w);
    }
    ushort4 o; o.x = f2bf(a0); o.y = f2bf(a1); o.z = f2bf(a2); o.w = f2bf(a3);
    *reinterpret_cast<ushort4*>(ct + (size_t)b * Lc * Dc + (size_t)t * Dc + c4) = o;
}

// ---------------------------------------------------------------------------
// LayerNorm: wave per row (64 lanes x 4 elems), shfl reduce, no barriers.
template <bool FINAL>
__global__ __launch_bounds__(256) void ln_k(
    const u16* __restrict__ in, const u16* __restrict__ g,
    const u16* __restrict__ be, void* __restrict__ out, const int* __restrict__ flag)
{
    const int wave = threadIdx.x >> 6, lane = threadIdx.x & 63;
    const int row = blockIdx.x * 4 + wave;
    const int c4 = lane * 4;
    const ushort4 u = *reinterpret_cast<const ushort4*>(in + (size_t)row * Dc + c4);
    float x[4] = {bf2f(u.x), bf2f(u.y), bf2f(u.z), bf2f(u.w)};
    float sm = x[0] + x[1] + x[2] + x[3];
    float sq = x[0]*x[0] + x[1]*x[1] + x[2]*x[2] + x[3]*x[3];
    #pragma unroll
    for (int off = 1; off < 64; off <<= 1) {
        sm += __shfl_xor(sm, off);
        sq += __shfl_xor(sq, off);
    }
    const float mean = sm * (1.f / 256.f);
    const float var = sq * (1.f / 256.f) - mean * mean;
    const float rstd = __frsqrt_rn(var + 1e-8f);
    const ushort4 gg = *reinterpret_cast<const ushort4*>(g + c4);
    const ushort4 bb = *reinterpret_cast<const ushort4*>(be + c4);
    float y[4];
    y[0] = (x[0] - mean) * rstd * bf2f(gg.x) + bf2f(bb.x);
    y[1] = (x[1] - mean) * rstd * bf2f(gg.y) + bf2f(bb.y);
    y[2] = (x[2] - mean) * rstd * bf2f(gg.z) + bf2f(bb.z);
    y[3] = (x[3] - mean) * rstd * bf2f(gg.w) + bf2f(bb.w);
    if (FINAL && *flag) {
        float4 o = make_float4(y[0], y[1], y[2], y[3]);
        *reinterpret_cast<float4*>((float*)out + (size_t)row * Dc + c4) = o;
    } else {
        ushort4 o; o.x = f2bf(y[0]); o.y = f2bf(y[1]); o.z = f2bf(y[2]); o.w = f2bf(y[3]);
        *reinterpret_cast<ushort4*>((u16*)out + (size_t)row * Dc + c4) = o;
    }
}

// ---------------------------------------------------------------------------
extern "C" void kernel_launch(void* const* d_in, const int* in_sizes, int n_in,
                              void* d_out, int out_size, void* d_ws, size_t ws_size,
                              hipStream_t stream)
{
    (void)in_sizes; (void)n_in; (void)out_size; (void)ws_size;

    const size_t BLD = (size_t)Bc * Lc * Dc;        // 8,388,608 elements
    const size_t SLOT = BLD * 2;                    // bf16 slot bytes: 16 MiB
    const long LD = (long)(Lc * Dc);
    char* ws = (char*)d_ws;
    u16* b0 = (u16*)(ws + 0 * SLOT);
    u16* b1 = (u16*)(ws + 1 * SLOT);
    u16* b2 = (u16*)(ws + 2 * SLOT);
    u16* b3 = (u16*)(ws + 3 * SLOT);
    u16* cx = (u16*)(ws + 4 * SLOT);                // converted x
    u16* G  = (u16*)(ws + 5 * SLOT);                // L*L bf16 = 2 MiB
    char* tail = ws + 5 * SLOT + (size_t)Lc * Lc * 2;
    u16* wts  = (u16*)tail;                         // 6*65536 + 10*256
    u16* wtsT = wts + 6 * 65536 + 10 * 256;         // 6*65536 transposed weights
    char* tail2 = (char*)(wtsT + 6 * 65536);
    float* hf  = (float*)(tail2 + 512);
    float* mv  = hf + Lc;
    int*   idx = (int*)(mv + Bc * Lc);
    float* wsm = (float*)(idx + 64);
    int*   flag = (int*)(wsm + Bc * TOPK);

    u16* vecs = wts + 6 * 65536;
    u16* cbv = vecs + 2 * 256;  u16* cbd = vecs + 3 * 256;
    u16* l1g = vecs + 4 * 256;  u16* l1b = vecs + 5 * 256;
    u16* cb1 = vecs + 6 * 256;  u16* cb2 = vecs + 7 * 256;
    u16* l2g = vecs + 8 * 256;  u16* l2b = vecs + 9 * 256;
    u16* wvT = wtsT + 2 * 65536;
    u16* wdT = wtsT + 3 * 65536; u16* w1T = wtsT + 4 * 65536; u16* w2T = wtsT + 5 * 65536;

    // 0. dtype detection + single-launch ingest to bf16 scratch
    detect_k<<<dim3(1), 256, 0, stream>>>((const u16*)d_in[0], flag);
    SrcPtrs sp;
    for (int i = 0; i < 17; ++i) sp.p[i] = d_in[i];
    ingest_all_k<<<dim3(34314), 256, 0, stream>>>(sp, cx, wts, flag);
    wtrans_k<<<dim3(8, 8, 6), 256, 0, stream>>>(wts, wtsT);

    // 1. filter kernel + circulant (bf16)
    build_h<<<dim3(4), 256, 0, stream>>>(hf);
    build_G<<<dim3((Lc * Lc) / 256), 256, 0, stream>>>(hf, G);

    // 2. cxT (b1), then Xf = G @ x (b0). Filtering commutes with projections;
    //    filtered biases vanish (DC bin masked).
    transpose_k<<<dim3(32, 8, 32), 256, 0, stream>>>(cx, b1);
    mgemm_k<0, false><<<dim3(4, 8, 32), 256, 0, stream>>>(
        G, nullptr, b1, nullptr, nullptr, b0, Lc, Dc, Lc, 0, LD, LD);

    // 3. qs/ks/vs = Xf @ {Wq,Wk,Wv} in ONE launch (z=3: contiguous weights/slots)
    mgemm_k<0, false><<<dim3(4, 256, 3), 256, 0, stream>>>(
        b0, nullptr, wtsT, nullptr, nullptr, b1, Bc * Lc, Dc, Dc, 0, 65536, (long)BLD);

    // 4. exact autocorrelation diag sums (r2-proven structure + reg-budget hint)
    hipMemsetAsync(mv, 0, (size_t)Bc * Lc * 4, stream);
    corr_k<<<dim3(2048), 256, 0, stream>>>(b1, b2, mv);

    // 5. vsT (b0; Xf dead), then flash MFMA attention (ctx -> b3)
    transpose_k<<<dim3(32, 8, 32), 256, 0, stream>>>(b3, b0);
    attn_k<<<dim3(16, 4, 32), 256, 0, stream>>>(b1, b2, b0, b3);

    // 6. top-k + per-batch softmax weights
    topk_k<<<dim3(1), 1024, 0, stream>>>(mv, idx, wsm);

    // 7. v = x @ Wv + bv (unfiltered; qs dead -> b1), time-delay agg -> b2
    const dim3 gProj(4, 256, 1);
    mgemm_k<0, false><<<gProj, 256, 0, stream>>>(cx, nullptr, wvT, cbv, nullptr, b1, Bc * Lc, Dc, Dc, 0, 0, 0);
    agg_k<<<dim3(256, 32), 256, 0, stream>>>(b1, idx, wsm, b2);

    // 8. d = (0.9*ct + 0.1*ctx) @ Wd + bd + x  -> b0 (vsT dead)
    mgemm_k<1, true><<<gProj, 256, 0, stream>>>(b2, b3, wdT, cbd, cx, b0, Bc * Lc, Dc, Dc, 0, 0, 0);

    // 9. LN1 -> h (b1)
    ln_k<false><<<dim3(8192), 256, 0, stream>>>(b0, l1g, l1b, b1, flag);

    // 10. FFN up + gelu -> b2; FFN down + h residual -> b3
    mgemm_k<2, false><<<gProj, 256, 0, stream>>>(b1, nullptr, w1T, cb1, nullptr, b2, Bc * Lc, Dc, Dc, 0, 0, 0);
    mgemm_k<1, false><<<gProj, 256, 0, stream>>>(b2, nullptr, w2T, cb2, b1, b3, Bc * Lc, Dc, Dc, 0, 0, 0);

    // 11. LN2 -> out (dtype per flag)
    ln_k<true><<<dim3(8192), 256, 0, stream>>>(b3, l2g, l2b, d_out, flag);
}

// Round 11
// 587.449 us; speedup vs baseline: 1.2358x; 1.0525x over previous
//
#include <hip/hip_runtime.h>
#include <hip/hip_bf16.h>
#include <math.h>

#define Lc 1024
#define Dc 256
#define Bc 32
#define Hc 4
#define Ec 64
#define TOPK 34
#define LEFTc 205

typedef unsigned short u16;
typedef __attribute__((ext_vector_type(8))) short bf16x8;
typedef __attribute__((ext_vector_type(4))) float f32x4;

__device__ __forceinline__ float bf2f(u16 u) {
    return __uint_as_float(((unsigned)u) << 16);
}
__device__ __forceinline__ u16 f2bf(float f) {        // round-to-nearest-even
    unsigned u = __float_as_uint(f);
    u += 0x7FFFu + ((u >> 16) & 1u);
    return (u16)(u >> 16);
}

// ---------------------------------------------------------------------------
// dtype probe: flag=1 means underlying data is fp32.
__global__ void detect_k(const u16* __restrict__ x, int* __restrict__ flag) {
    __shared__ int cnt;
    if (threadIdx.x == 0) cnt = 0;
    __syncthreads();
    int bad = 0;
    for (int i = threadIdx.x; i < 4096; i += 256) {
        float a = fabsf(bf2f(x[i]));
        if (!(a == 0.0f || (a >= 1e-8f && a <= 1e8f))) bad++;
    }
    atomicAdd(&cnt, bad);
    __syncthreads();
    if (threadIdx.x == 0) *flag = (cnt > 512) ? 1 : 0;
}

// One launch ingests all 17 inputs into bf16 scratch. 8 elems/thread,
// vectorized loads/stores (region boundaries are multiples of 8).
struct SrcPtrs { const void* p[17]; };
__global__ __launch_bounds__(256) void ingest_all_k(
    SrcPtrs sp, u16* __restrict__ cx, u16* __restrict__ wts, const int* __restrict__ flag)
{
    const long NB = (long)Bc * Lc * Dc;             // 8,388,608
    long e = ((long)blockIdx.x * 256 + threadIdx.x) * 8;
    const int fp = *flag;
    const void* src; u16* dst; long off;
    if (e < NB) {
        src = sp.p[0]; dst = cx; off = e;
    } else {
        long j = e - NB;
        if (j < 6L * 65536) {                       // Wq,Wk,Wv,Wd,W1,W2
            const int w = (int)(j >> 16); off = j & 65535;
            const int wsidx[6] = {1, 3, 5, 7, 11, 13};
            src = sp.p[wsidx[w]]; dst = wts + (long)w * 65536;
        } else {
            long k2 = j - 6L * 65536;
            if (k2 >= 2560) return;                 // bq,bk,bv,bd,l1g,l1b,b1,b2,l2g,l2b
            const int v = (int)(k2 >> 8); off = k2 & 255;
            const int vsidx[10] = {2, 4, 6, 8, 9, 10, 12, 14, 15, 16};
            src = sp.p[vsidx[v]]; dst = wts + 6L * 65536 + (long)v * 256;
        }
    }
    u16 o[8];
    if (fp) {
        const float* s = (const float*)src + off;
        const float4 a = *(const float4*)s;
        const float4 b2 = *(const float4*)(s + 4);
        o[0]=f2bf(a.x); o[1]=f2bf(a.y); o[2]=f2bf(a.z); o[3]=f2bf(a.w);
        o[4]=f2bf(b2.x); o[5]=f2bf(b2.y); o[6]=f2bf(b2.z); o[7]=f2bf(b2.w);
    } else {
        const ushort4* s = (const ushort4*)((const u16*)src + off);
        const ushort4 a = s[0], b2 = s[1];
        o[0]=a.x; o[1]=a.y; o[2]=a.z; o[3]=a.w;
        o[4]=b2.x; o[5]=b2.y; o[6]=b2.z; o[7]=b2.w;
    }
    *(ushort4*)(dst + off)     = make_ushort4(o[0], o[1], o[2], o[3]);
    *(ushort4*)(dst + off + 4) = make_ushort4(o[4], o[5], o[6], o[7]);
}

// ---------------------------------------------------------------------------
// Band-pass kernel h[d] = (1/L)(2*sum_{f=205}^{511} cos(2pi f d/L) + cos(pi d))
// Exact angle reduction (integer mod 1024) + HW cosf: error ~1e-5 << bf16 eps.
__global__ void build_h(float* __restrict__ hf) {
    int d = blockIdx.x * blockDim.x + threadIdx.x;
    if (d >= Lc) return;
    float s = 0.f;
    for (int f = LEFTc; f < 512; ++f) {
        int m = (f * d) & (Lc - 1);
        s += __cosf((float)m * 6.135923151542565e-3f);   // 2pi/1024
    }
    float ny = (d & 1) ? -1.f : 1.f;
    hf[d] = (2.f * s + ny) * (1.f / 1024.f);
}

__global__ void build_G(const float* __restrict__ hf, u16* __restrict__ G) {
    int i = blockIdx.x * 256 + threadIdx.x;
    int t = i >> 10, s = i & (Lc - 1);
    G[i] = f2bf(hf[(t - s) & (Lc - 1)]);
}

// ---------------------------------------------------------------------------
// Transpose (B, L, D) bf16 -> (B, D, L) bf16.
__global__ __launch_bounds__(256) void transpose_k(
    const u16* __restrict__ in, u16* __restrict__ out)
{
    __shared__ u16 t[32][33];
    const int l0 = blockIdx.x * 32, d0 = blockIdx.y * 32, b = blockIdx.z;
    const int tx = threadIdx.x & 31, ty = threadIdx.x >> 5;
    const u16* ib = in + (size_t)b * Lc * Dc;
    #pragma unroll
    for (int i = 0; i < 4; ++i)
        t[ty + i * 8][tx] = ib[(size_t)(l0 + ty + i * 8) * Dc + d0 + tx];
    __syncthreads();
    u16* ob = out + (size_t)b * Dc * Lc;
    #pragma unroll
    for (int i = 0; i < 4; ++i)
        ob[(size_t)(d0 + ty + i * 8) * Lc + l0 + tx] = t[tx][ty + i * 8];
}

// Transpose the six 256x256 weight matrices (contiguous): dst[z][n][k]=src[z][k][n]
__global__ __launch_bounds__(256) void wtrans_k(
    const u16* __restrict__ src, u16* __restrict__ dst)
{
    __shared__ u16 t[32][33];
    const int c0 = blockIdx.x * 32, r0 = blockIdx.y * 32;
    const u16* s = src + (size_t)blockIdx.z * 65536;
    u16* d = dst + (size_t)blockIdx.z * 65536;
    const int tx = threadIdx.x & 31, ty = threadIdx.x >> 5;
    #pragma unroll
    for (int i = 0; i < 4; ++i)
        t[ty + i * 8][tx] = s[(r0 + ty + i * 8) * 256 + c0 + tx];
    __syncthreads();
    #pragma unroll
    for (int i = 0; i < 4; ++i)
        d[(c0 + ty + i * 8) * 256 + r0 + tx] = t[tx][ty + i * 8];
}

// ---------------------------------------------------------------------------
// MFMA GEMM: C[M,N] = A[M,K] @ B[K,N], bf16 in/out, fp32 accum. BT is (N,K).
// Block = 4 waves, 128x64 C tile; wave owns 32 rows x 64 cols.
// BT chunk (64 n x 128 k) staged in LDS, frag-ordered + XOR-swizzled.
// T14 async staging: regs hold next chunk; global latency hides under MFMA.
// EPI: 0=+bias, 1=+bias+bf16 resid, 2=gelu(+bias). ACOMB: A=0.9A+0.1A2.
template <int EPI, bool ACOMB>
__global__ __launch_bounds__(256) void mgemm_k(
    const u16* __restrict__ Abase, const u16* __restrict__ A2base,
    const u16* __restrict__ BTbase, const u16* __restrict__ bias,
    const u16* __restrict__ resid, u16* __restrict__ Cbase,
    int M, int N, int K, long strA, long strBT, long strC)
{
    const int z = blockIdx.z;
    const u16* A  = Abase + (size_t)z * strA;
    const u16* BT = BTbase + (size_t)z * strBT;
    u16* C        = Cbase + (size_t)z * strC;
    const int tid = threadIdx.x;
    const int wave = tid >> 6, lane = tid & 63;
    const int m16 = lane & 15, quad = lane >> 4;
    const int m0 = blockIdx.y * 128 + wave * 32;
    const int n0 = blockIdx.x * 64;

    __shared__ __align__(16) u16 sB[8192];   // 16 KB

    const u16* arow0 = A + (size_t)(m0 + m16) * K + quad * 8;
    const u16* arow1 = arow0 + (size_t)16 * K;
    const u16* a2row0 = ACOMB ? (A2base + (size_t)z * strA + (size_t)(m0 + m16) * K + quad * 8) : nullptr;
    const u16* a2row1 = ACOMB ? (a2row0 + (size_t)16 * K) : nullptr;

    // per-thread staging addresses (fixed across kc)
    const u16* bgp[4];
    u16* bls[4];
    #pragma unroll
    for (int i = 0; i < 4; ++i) {
        const int c = tid + i * 256;
        const int nr = c >> 4, ko = c & 15;
        bgp[i] = BT + (size_t)(n0 + nr) * K + ko * 8;
        bls[i] = sB + ((nr >> 4) * 4 + (ko >> 2)) * 512 + (ko & 3) * 128
                    + (((nr & 15) ^ (ko & 3))) * 8;
    }

    bf16x8 breg[4];
    #pragma unroll
    for (int i = 0; i < 4; ++i) breg[i] = *(const bf16x8*)(bgp[i]);

    f32x4 acc[2][4] = {};

    #pragma unroll 1
    for (int kc = 0; kc < K; kc += 128) {
        #pragma unroll
        for (int i = 0; i < 4; ++i) *(bf16x8*)(bls[i]) = breg[i];
        __syncthreads();
        if (kc + 128 < K) {
            #pragma unroll
            for (int i = 0; i < 4; ++i) breg[i] = *(const bf16x8*)(bgp[i] + kc + 128);
        }
        #pragma unroll
        for (int kf = 0; kf < 4; ++kf) {
            bf16x8 a0 = *(const bf16x8*)(arow0 + kc + kf * 32);
            bf16x8 a1 = *(const bf16x8*)(arow1 + kc + kf * 32);
            if (ACOMB) {
                const bf16x8 x0 = *(const bf16x8*)(a2row0 + kc + kf * 32);
                const bf16x8 x1 = *(const bf16x8*)(a2row1 + kc + kf * 32);
                #pragma unroll
                for (int j = 0; j < 8; ++j) {
                    a0[j] = (short)f2bf(0.9f * bf2f((u16)a0[j]) + 0.1f * bf2f((u16)x0[j]));
                    a1[j] = (short)f2bf(0.9f * bf2f((u16)a1[j]) + 0.1f * bf2f((u16)x1[j]));
                }
            }
            #pragma unroll
            for (int nt = 0; nt < 4; ++nt) {
                const bf16x8 bf = *(const bf16x8*)(sB + (nt * 4 + kf) * 512 + quad * 128
                                                      + ((m16 ^ quad)) * 8);
                acc[0][nt] = __builtin_amdgcn_mfma_f32_16x16x32_bf16(a0, bf, acc[0][nt], 0, 0, 0);
                acc[1][nt] = __builtin_amdgcn_mfma_f32_16x16x32_bf16(a1, bf, acc[1][nt], 0, 0, 0);
            }
        }
        __syncthreads();
    }

    #pragma unroll
    for (int ms = 0; ms < 2; ++ms) {
        #pragma unroll
        for (int nt = 0; nt < 4; ++nt) {
            const int col = n0 + nt * 16 + m16;
            const float bv = bias ? bf2f(bias[col]) : 0.f;
            #pragma unroll
            for (int r = 0; r < 4; ++r) {
                const size_t off = (size_t)(m0 + ms * 16 + quad * 4 + r) * N + col;
                float v = acc[ms][nt][r] + bv;
                if (EPI == 1) v += bf2f(resid[off]);
                if (EPI == 2) v = 0.5f * v * (1.0f + erff(v * 0.70710678118654752f));
                C[off] = f2bf(v);
            }
        }
    }
}

// ---------------------------------------------------------------------------
// Exact autocorrelation diag sums via full-D MFMA. Grid/swizzle/reduction
// IDENTICAL to the r2-proven 108us structure; only the register-level loop is
// reordered (k0-outer) with k-row DEDUP: for a wave, u spans 4 consecutive
// values and s = u - A - al, so the 16 (ui,al) pairs touch only 7 distinct
// k-rows. Loads/wave drop 160 -> 88 (4 q + 7 k per k0-slice), and each
// k0 iteration is a natural group of 11 independent loads ahead of its 16
// MFMAs -- the deep-issue pattern r5's foldable double-buffer failed to get.
// tau = 16(A+al) + (quad*4+r-m16) is ui-independent, so acc[al] accumulation
// is unchanged (fp reorder only).
// JOURNAL: 108us standalone baseline. Full restructures all LOST (reg-dbuf
// 133, LDS-ring 197, mgemm-clone 202, LDS-atomic fusion 732, merged-launch
// 302); launch_bounds(256,1) hint was a no-op (VGPR stayed 76).
__global__ __launch_bounds__(256) void corr_k(
    const u16* __restrict__ qs, const u16* __restrict__ ks, float* __restrict__ mv)
{
    const int l = blockIdx.x;                       // 0..2047
    const int b = ((l & 7) << 2) | ((l >> 3) & 3);  // same b -> same XCD (mod-8 rr)
    const int rest = l >> 5;                        // 0..63
    const int g = rest & 15;                        // shift group: a = g*4 + al
    const int uq = rest >> 4;                       // u quarter
    const int wave = threadIdx.x >> 6, lane = threadIdx.x & 63;
    const int m16 = lane & 15, quad = lane >> 4;
    const size_t base = (size_t)b * Lc * Dc;

    __shared__ float red[4][124];                   // [wave][al*31 + d+15]
    for (int i = threadIdx.x; i < 4 * 124; i += 256) ((float*)red)[i] = 0.f;
    __syncthreads();

    const int u0 = uq * 16 + wave * 4;              // wave's 4 u-groups: u0..u0+3
    const u16* qr[4];
    const u16* kr[7];                               // s_unwr = u0 - g*4 - 3 + d
    #pragma unroll
    for (int ui = 0; ui < 4; ++ui)
        qr[ui] = qs + base + (size_t)((u0 + ui) * 16 + m16) * Dc + quad * 8;
    #pragma unroll
    for (int d = 0; d < 7; ++d) {
        const int s = (u0 - g * 4 - 3 + d) & 63;
        kr[d] = ks + base + (size_t)(s * 16 + m16) * Dc + quad * 8;
    }

    f32x4 acc[4] = {};
    #pragma unroll 1
    for (int k0 = 0; k0 < Dc; k0 += 32) {
        const bf16x8 qv0 = *(const bf16x8*)(qr[0] + k0);
        const bf16x8 qv1 = *(const bf16x8*)(qr[1] + k0);
        const bf16x8 qv2 = *(const bf16x8*)(qr[2] + k0);
        const bf16x8 qv3 = *(const bf16x8*)(qr[3] + k0);
        const bf16x8 kv0 = *(const bf16x8*)(kr[0] + k0);
        const bf16x8 kv1 = *(const bf16x8*)(kr[1] + k0);
        const bf16x8 kv2 = *(const bf16x8*)(kr[2] + k0);
        const bf16x8 kv3 = *(const bf16x8*)(kr[3] + k0);
        const bf16x8 kv4 = *(const bf16x8*)(kr[4] + k0);
        const bf16x8 kv5 = *(const bf16x8*)(kr[5] + k0);
        const bf16x8 kv6 = *(const bf16x8*)(kr[6] + k0);
        // acc[al] += qv[ui] x kv[ui - al + 3]
        acc[0] = __builtin_amdgcn_mfma_f32_16x16x32_bf16(qv0, kv3, acc[0], 0, 0, 0);
        acc[1] = __builtin_amdgcn_mfma_f32_16x16x32_bf16(qv0, kv2, acc[1], 0, 0, 0);
        acc[2] = __builtin_amdgcn_mfma_f32_16x16x32_bf16(qv0, kv1, acc[2], 0, 0, 0);
        acc[3] = __builtin_amdgcn_mfma_f32_16x16x32_bf16(qv0, kv0, acc[3], 0, 0, 0);
        acc[0] = __builtin_amdgcn_mfma_f32_16x16x32_bf16(qv1, kv4, acc[0], 0, 0, 0);
        acc[1] = __builtin_amdgcn_mfma_f32_16x16x32_bf16(qv1, kv3, acc[1], 0, 0, 0);
        acc[2] = __builtin_amdgcn_mfma_f32_16x16x32_bf16(qv1, kv2, acc[2], 0, 0, 0);
        acc[3] = __builtin_amdgcn_mfma_f32_16x16x32_bf16(qv1, kv1, acc[3], 0, 0, 0);
        acc[0] = __builtin_amdgcn_mfma_f32_16x16x32_bf16(qv2, kv5, acc[0], 0, 0, 0);
        acc[1] = __builtin_amdgcn_mfma_f32_16x16x32_bf16(qv2, kv4, acc[1], 0, 0, 0);
        acc[2] = __builtin_amdgcn_mfma_f32_16x16x32_bf16(qv2, kv3, acc[2], 0, 0, 0);
        acc[3] = __builtin_amdgcn_mfma_f32_16x16x32_bf16(qv2, kv2, acc[3], 0, 0, 0);
        acc[0] = __builtin_amdgcn_mfma_f32_16x16x32_bf16(qv3, kv6, acc[0], 0, 0, 0);
        acc[1] = __builtin_amdgcn_mfma_f32_16x16x32_bf16(qv3, kv5, acc[1], 0, 0, 0);
        acc[2] = __builtin_amdgcn_mfma_f32_16x16x32_bf16(qv3, kv4, acc[2], 0, 0, 0);
        acc[3] = __builtin_amdgcn_mfma_f32_16x16x32_bf16(qv3, kv3, acc[3], 0, 0, 0);
    }

    #pragma unroll
    for (int al = 0; al < 4; ++al)
        #pragma unroll
        for (int r = 0; r < 4; ++r)
            unsafeAtomicAdd(&red[wave][al * 31 + quad * 4 + r - m16 + 15], acc[al][r]);
    __syncthreads();

    if (threadIdx.x < 124) {
        const int al = threadIdx.x / 31, dd = threadIdx.x % 31;   // d = dd - 15
        const float s = red[0][threadIdx.x] + red[1][threadIdx.x] +
                        red[2][threadIdx.x] + red[3][threadIdx.x];
        unsafeAtomicAdd(&mv[b * Lc + (((g * 4 + al) * 16 + dd - 15) & (Lc - 1))], s);
    }
}

// ---------------------------------------------------------------------------
// Flash MFMA attention, 64 Q rows/block, LDS-staged K/V tiles (frag-ordered,
// XOR-swizzled), per-wave P in LDS (XOR-swizzled stores -> conflict-free).
// T14 async staging: next K/V tile loaded to regs during QK+PV compute.
// No max-subtraction (|S/8| << 88); O scaled at end. exp folded to a single
// exp2 (VALU is the busier pipe: 29% vs MFMA 11%).
// NOTE: corr fusion (r3/r4) and corr merge (r9) both LOSE -- keep separate.
__global__ __launch_bounds__(256) void attn_k(
    const u16* __restrict__ qs, const u16* __restrict__ ks,
    const u16* __restrict__ vsT, u16* __restrict__ ctx)
{
    const int lt = blockIdx.x, h = blockIdx.y, b = blockIdx.z;

    __shared__ __align__(16) u16 sK[8192];   // 128 s x 64 e, frag-ordered+swz
    __shared__ __align__(16) u16 sV[8192];   // 64 e x 128 s (V^T), frag-ordered+swz
    __shared__ __align__(16) u16 sP[8192];   // 4 waves x (16 q x 128 s), swz

    const int tid  = threadIdx.x;
    const int wave = tid >> 6;
    const int lane = tid & 63;
    const int m16  = lane & 15;
    const int quad = lane >> 4;
    const int l0   = lt * 64;
    const size_t base = (size_t)b * Lc * Dc + (size_t)h * Ec;
    const size_t vtbase = ((size_t)b * Dc + (size_t)h * Ec) * Lc;

    const u16* qrow = qs + base + (size_t)(l0 + wave * 16 + m16) * Dc + quad * 8;
    const bf16x8 qa0 = *(const bf16x8*)(qrow);
    const bf16x8 qa1 = *(const bf16x8*)(qrow + 32);

    // per-thread staging addresses (fixed across s0)
    const u16* kgp[4]; const u16* vgp[4];
    u16* kls[4]; u16* vls[4];
    #pragma unroll
    for (int i = 0; i < 4; ++i) {
        const int c = tid + i * 256;
        const int sr = c >> 3, eo = c & 7;
        kgp[i] = ks + base + (size_t)sr * Dc + eo * 8;
        kls[i] = sK + ((sr >> 4) * 2 + (eo >> 2)) * 512 + (eo & 3) * 128
                    + (((sr & 15) ^ (eo & 3))) * 8;
        const int er = c >> 4, so = c & 15;
        vgp[i] = vsT + vtbase + (size_t)er * Lc + so * 8;
        vls[i] = sV + ((er >> 4) * 4 + (so >> 2)) * 512 + (so & 3) * 128
                    + (((er & 15) ^ (so & 3))) * 8;
    }

    bf16x8 kreg[4], vreg[4];
    #pragma unroll
    for (int i = 0; i < 4; ++i) {
        kreg[i] = *(const bf16x8*)(kgp[i]);
        vreg[i] = *(const bf16x8*)(vgp[i]);
    }

    f32x4 o[4] = {};
    float rs[4] = {0.f, 0.f, 0.f, 0.f};

    const int rsw = m16 ^ quad;                       // K/V swizzled frag-row
    const int hrd = ((quad & 1) << 1) | (m16 >> 3);   // P read swizzle
    const int prd = (m16 ^ hrd) * 8;

    #pragma unroll 1
    for (int s0 = 0; s0 < Lc; s0 += 128) {
        // write staged tile (previous PV reads fenced by trailing barrier)
        #pragma unroll
        for (int i = 0; i < 4; ++i) {
            *(bf16x8*)(kls[i]) = kreg[i];
            *(bf16x8*)(vls[i]) = vreg[i];
        }
        __syncthreads();
        // prefetch next tile: latency hides under QK + PV
        if (s0 + 128 < Lc) {
            #pragma unroll
            for (int i = 0; i < 4; ++i) {
                kreg[i] = *(const bf16x8*)(kgp[i] + (size_t)(s0 + 128) * Dc);
                vreg[i] = *(const bf16x8*)(vgp[i] + (s0 + 128));
            }
        }

        // ---- QK + fused exp + rowsum; P -> per-wave LDS (A-frag order, swz)
        #pragma unroll
        for (int st = 0; st < 8; ++st) {
            const bf16x8 kb0 = *(const bf16x8*)(sK + (st * 2 + 0) * 512 + quad * 128 + rsw * 8);
            const bf16x8 kb1 = *(const bf16x8*)(sK + (st * 2 + 1) * 512 + quad * 128 + rsw * 8);
            f32x4 c4 = {0.f, 0.f, 0.f, 0.f};
            c4 = __builtin_amdgcn_mfma_f32_16x16x32_bf16(qa0, kb0, c4, 0, 0, 0);
            c4 = __builtin_amdgcn_mfma_f32_16x16x32_bf16(qa1, kb1, c4, 0, 0, 0);
            const int q2 = ((st & 1) << 1) | (m16 >> 3);
            const int hst = ((q2 & 1) << 1) | (quad >> 1);
            u16* pw = sP + wave * 2048 + (st >> 1) * 512 + q2 * 128 + (m16 & 7);
            #pragma unroll
            for (int r = 0; r < 4; ++r) {
                // exp(S/8) = exp2(S * 0.125*log2(e)) -- one mul + one v_exp
                const float p = __builtin_amdgcn_exp2f(c4[r] * 0.1803368801111204f);
                rs[r] += p;
                pw[(((quad * 4 + r) ^ hst)) * 8] = f2bf(p);
            }
        }
        __syncthreads();

        // ---- PV accumulate (A from sP swizzled, B from sV)
        const bf16x8 a0 = *(const bf16x8*)(sP + wave * 2048 + 0 * 512 + quad * 128 + prd);
        const bf16x8 a1 = *(const bf16x8*)(sP + wave * 2048 + 1 * 512 + quad * 128 + prd);
        const bf16x8 a2 = *(const bf16x8*)(sP + wave * 2048 + 2 * 512 + quad * 128 + prd);
        const bf16x8 a3 = *(const bf16x8*)(sP + wave * 2048 + 3 * 512 + quad * 128 + prd);
        #pragma unroll
        for (int nt = 0; nt < 4; ++nt) {
            o[nt] = __builtin_amdgcn_mfma_f32_16x16x32_bf16(a0, *(const bf16x8*)(sV + (nt * 4 + 0) * 512 + quad * 128 + rsw * 8), o[nt], 0, 0, 0);
            o[nt] = __builtin_amdgcn_mfma_f32_16x16x32_bf16(a1, *(const bf16x8*)(sV + (nt * 4 + 1) * 512 + quad * 128 + rsw * 8), o[nt], 0, 0, 0);
            o[nt] = __builtin_amdgcn_mfma_f32_16x16x32_bf16(a2, *(const bf16x8*)(sV + (nt * 4 + 2) * 512 + quad * 128 + rsw * 8), o[nt], 0, 0, 0);
            o[nt] = __builtin_amdgcn_mfma_f32_16x16x32_bf16(a3, *(const bf16x8*)(sV + (nt * 4 + 3) * 512 + quad * 128 + rsw * 8), o[nt], 0, 0, 0);
        }
        __syncthreads();
    }

    // rowsum reduce across the 16 lanes of each quad group (rows are wave-local)
    #pragma unroll
    for (int off = 1; off < 16; off <<= 1) {
        #pragma unroll
        for (int r = 0; r < 4; ++r) rs[r] += __shfl_xor(rs[r], off);
    }
    #pragma unroll
    for (int nt = 0; nt < 4; ++nt) {
        #pragma unroll
        for (int r = 0; r < 4; ++r)
            ctx[base + (size_t)(l0 + wave * 16 + quad * 4 + r) * Dc + nt * 16 + m16] =
                f2bf(o[nt][r] / rs[r]);
    }
}

// ---------------------------------------------------------------------------
// Top-34 over mean-over-batch of mv (shfl-based), then per-batch softmax weights.
__global__ __launch_bounds__(1024) void topk_k(
    const float* __restrict__ mv, int* __restrict__ idx_g, float* __restrict__ w_g)
{
    __shared__ float wvs[16];
    __shared__ int   wis[16];
    __shared__ int   widx;
    __shared__ int   sidx[TOPK];
    const int tid = threadIdx.x;
    const int lane = tid & 63;
    const int wv_id = tid >> 6;

    float g = 0.f;
    for (int b = 0; b < Bc; ++b) g += mv[b * Lc + tid];

    for (int j = 0; j < TOPK; ++j) {
        float v = g; int ix = tid;
        #pragma unroll
        for (int off = 32; off > 0; off >>= 1) {
            const float ov = __shfl_xor(v, off);
            const int   oi = __shfl_xor(ix, off);
            if (ov > v || (ov == v && oi < ix)) { v = ov; ix = oi; }
        }
        if (lane == 0) { wvs[wv_id] = v; wis[wv_id] = ix; }
        __syncthreads();
        if (tid == 0) {
            float bv = wvs[0]; int bi = wis[0];
            for (int u = 1; u < 16; ++u)
                if (wvs[u] > bv || (wvs[u] == bv && wis[u] < bi)) { bv = wvs[u]; bi = wis[u]; }
            widx = bi; sidx[j] = bi; idx_g[j] = bi;
        }
        __syncthreads();
        if (tid == widx) g = -3e38f;
        __syncthreads();
    }
    if (tid < Bc) {
        float wv[TOPK];
        float mx = -3e38f;
        for (int j = 0; j < TOPK; ++j) {
            wv[j] = mv[tid * Lc + sidx[j]] * (1.0f / (float)Dc);
            mx = fmaxf(mx, wv[j]);
        }
        float sum = 0.f;
        for (int j = 0; j < TOPK; ++j) { wv[j] = expf(wv[j] - mx); sum += wv[j]; }
        for (int j = 0; j < TOPK; ++j) w_g[tid * TOPK + j] = wv[j] / sum;
    }
}

// Time-delay agg: wave per t (64 lanes x ushort4 = 256 cols), 4 t per block.
__global__ __launch_bounds__(256) void agg_k(
    const u16* __restrict__ v, const int* __restrict__ idx,
    const float* __restrict__ w, u16* __restrict__ ct)
{
    const int b = blockIdx.y;
    const int t = blockIdx.x * 4 + (threadIdx.x >> 6);
    const int lane = threadIdx.x & 63;
    __shared__ int   sidx[TOPK];
    __shared__ float sw[TOPK];
    if (threadIdx.x < TOPK) { sidx[threadIdx.x] = idx[threadIdx.x]; sw[threadIdx.x] = w[b * TOPK + threadIdx.x]; }
    __syncthreads();
    const u16* vb = v + (size_t)b * Lc * Dc;
    const int c4 = lane * 4;
    float a0 = 0.f, a1 = 0.f, a2 = 0.f, a3 = 0.f;
    for (int j = 0; j < TOPK; ++j) {
        const float wj = sw[j];
        const ushort4 u = *reinterpret_cast<const ushort4*>(
            vb + (size_t)((t + sidx[j]) & (Lc - 1)) * Dc + c4);
        a0 += wj * bf2f(u.x); a1 += wj * bf2f(u.y);
        a2 += wj * bf2f(u.z); a3 += wj * bf2f(u.w);
    }
    ushort4 o; o.x = f2bf(a0); o.y = f2bf(a1); o.z = f2bf(a2); o.w = f2bf(a3);
    *reinterpret_cast<ushort4*>(ct + (size_t)b * Lc * Dc + (size_t)t * Dc + c4) = o;
}

// ---------------------------------------------------------------------------
// LayerNorm: wave per row (64 lanes x 4 elems), shfl reduce, no barriers.
template <bool FINAL>
__global__ __launch_bounds__(256) void ln_k(
    const u16* __restrict__ in, const u16* __restrict__ g,
    const u16* __restrict__ be, void* __restrict__ out, const int* __restrict__ flag)
{
    const int wave = threadIdx.x >> 6, lane = threadIdx.x & 63;
    const int row = blockIdx.x * 4 + wave;
    const int c4 = lane * 4;
    const ushort4 u = *reinterpret_cast<const ushort4*>(in + (size_t)row * Dc + c4);
    float x[4] = {bf2f(u.x), bf2f(u.y), bf2f(u.z), bf2f(u.w)};
    float sm = x[0] + x[1] + x[2] + x[3];
    float sq = x[0]*x[0] + x[1]*x[1] + x[2]*x[2] + x[3]*x[3];
    #pragma unroll
    for (int off = 1; off < 64; off <<= 1) {
        sm += __shfl_xor(sm, off);
        sq += __shfl_xor(sq, off);
    }
    const float mean = sm * (1.f / 256.f);
    const float var = sq * (1.f / 256.f) - mean * mean;
    const float rstd = __frsqrt_rn(var + 1e-8f);
    const ushort4 gg = *reinterpret_cast<const ushort4*>(g + c4);
    const ushort4 bb = *reinterpret_cast<const ushort4*>(be + c4);
    float y[4];
    y[0] = (x[0] - mean) * rstd * bf2f(gg.x) + bf2f(bb.x);
    y[1] = (x[1] - mean) * rstd * bf2f(gg.y) + bf2f(bb.y);
    y[2] = (x[2] - mean) * rstd * bf2f(gg.z) + bf2f(bb.z);
    y[3] = (x[3] - mean) * rstd * bf2f(gg.w) + bf2f(bb.w);
    if (FINAL && *flag) {
        float4 o = make_float4(y[0], y[1], y[2], y[3]);
        *reinterpret_cast<float4*>((float*)out + (size_t)row * Dc + c4) = o;
    } else {
        ushort4 o; o.x = f2bf(y[0]); o.y = f2bf(y[1]); o.z = f2bf(y[2]); o.w = f2bf(y[3]);
        *reinterpret_cast<ushort4*>((u16*)out + (size_t)row * Dc + c4) = o;
    }
}

// ---------------------------------------------------------------------------
extern "C" void kernel_launch(void* const* d_in, const int* in_sizes, int n_in,
                              void* d_out, int out_size, void* d_ws, size_t ws_size,
                              hipStream_t stream)
{
    (void)in_sizes; (void)n_in; (void)out_size; (void)ws_size;

    const size_t BLD = (size_t)Bc * Lc * Dc;        // 8,388,608 elements
    const size_t SLOT = BLD * 2;                    // bf16 slot bytes: 16 MiB
    const long LD = (long)(Lc * Dc);
    char* ws = (char*)d_ws;
    u16* b0 = (u16*)(ws + 0 * SLOT);
    u16* b1 = (u16*)(ws + 1 * SLOT);
    u16* b2 = (u16*)(ws + 2 * SLOT);
    u16* b3 = (u16*)(ws + 3 * SLOT);
    u16* cx = (u16*)(ws + 4 * SLOT);                // converted x
    u16* G  = (u16*)(ws + 5 * SLOT);                // L*L bf16 = 2 MiB
    char* tail = ws + 5 * SLOT + (size_t)Lc * Lc * 2;
    u16* wts  = (u16*)tail;                         // 6*65536 + 10*256
    u16* wtsT = wts + 6 * 65536 + 10 * 256;         // 6*65536 transposed weights
    char* tail2 = (char*)(wtsT + 6 * 65536);
    float* hf  = (float*)(tail2 + 512);
    float* mv  = hf + Lc;
    int*   idx = (int*)(mv + Bc * Lc);
    float* wsm = (float*)(idx + 64);
    int*   flag = (int*)(wsm + Bc * TOPK);

    u16* vecs = wts + 6 * 65536;
    u16* cbv = vecs + 2 * 256;  u16* cbd = vecs + 3 * 256;
    u16* l1g = vecs + 4 * 256;  u16* l1b = vecs + 5 * 256;
    u16* cb1 = vecs + 6 * 256;  u16* cb2 = vecs + 7 * 256;
    u16* l2g = vecs + 8 * 256;  u16* l2b = vecs + 9 * 256;
    u16* wvT = wtsT + 2 * 65536;
    u16* wdT = wtsT + 3 * 65536; u16* w1T = wtsT + 4 * 65536; u16* w2T = wtsT + 5 * 65536;

    // 0. dtype detection + single-launch vectorized ingest to bf16 scratch
    detect_k<<<dim3(1), 256, 0, stream>>>((const u16*)d_in[0], flag);
    SrcPtrs sp;
    for (int i = 0; i < 17; ++i) sp.p[i] = d_in[i];
    ingest_all_k<<<dim3(4290), 256, 0, stream>>>(sp, cx, wts, flag);
    wtrans_k<<<dim3(8, 8, 6), 256, 0, stream>>>(wts, wtsT);

    // 1. filter kernel + circulant (bf16)
    build_h<<<dim3(4), 256, 0, stream>>>(hf);
    build_G<<<dim3((Lc * Lc) / 256), 256, 0, stream>>>(hf, G);

    // 2. cxT (b1), then Xf = G @ x (b0). Filtering commutes with projections;
    //    filtered biases vanish (DC bin masked).
    transpose_k<<<dim3(32, 8, 32), 256, 0, stream>>>(cx, b1);
    mgemm_k<0, false><<<dim3(4, 8, 32), 256, 0, stream>>>(
        G, nullptr, b1, nullptr, nullptr, b0, Lc, Dc, Lc, 0, LD, LD);

    // 3. qs/ks/vs = Xf @ {Wq,Wk,Wv} in ONE launch (z=3: contiguous weights/slots)
    mgemm_k<0, false><<<dim3(4, 256, 3), 256, 0, stream>>>(
        b0, nullptr, wtsT, nullptr, nullptr, b1, Bc * Lc, Dc, Dc, 0, 65536, (long)BLD);

    // 4. exact autocorrelation diag sums (r2 grid/reduction + dedup'd loop)
    hipMemsetAsync(mv, 0, (size_t)Bc * Lc * 4, stream);
    corr_k<<<dim3(2048), 256, 0, stream>>>(b1, b2, mv);

    // 5. vsT (b0; Xf dead), then flash MFMA attention (ctx -> b3)
    transpose_k<<<dim3(32, 8, 32), 256, 0, stream>>>(b3, b0);
    attn_k<<<dim3(16, 4, 32), 256, 0, stream>>>(b1, b2, b0, b3);

    // 6. top-k + per-batch softmax weights
    topk_k<<<dim3(1), 1024, 0, stream>>>(mv, idx, wsm);

    // 7. v = x @ Wv + bv (unfiltered; qs dead -> b1), time-delay agg -> b2
    const dim3 gProj(4, 256, 1);
    mgemm_k<0, false><<<gProj, 256, 0, stream>>>(cx, nullptr, wvT, cbv, nullptr, b1, Bc * Lc, Dc, Dc, 0, 0, 0);
    agg_k<<<dim3(256, 32), 256, 0, stream>>>(b1, idx, wsm, b2);

    // 8. d = (0.9*ct + 0.1*ctx) @ Wd + bd + x  -> b0 (vsT dead)
    mgemm_k<1, true><<<gProj, 256, 0, stream>>>(b2, b3, wdT, cbd, cx, b0, Bc * Lc, Dc, Dc, 0, 0, 0);

    // 9. LN1 -> h (b1)
    ln_k<false><<<dim3(8192), 256, 0, stream>>>(b0, l1g, l1b, b1, flag);

    // 10. FFN up + gelu -> b2; FFN down + h residual -> b3
    mgemm_k<2, false><<<gProj, 256, 0, stream>>>(b1, nullptr, w1T, cb1, nullptr, b2, Bc * Lc, Dc, Dc, 0, 0, 0);
    mgemm_k<1, false><<<gProj, 256, 0, stream>>>(b2, nullptr, w2T, cb2, b1, b3, Bc * Lc, Dc, Dc, 0, 0, 0);

    // 11. LN2 -> out (dtype per flag)
    ln_k<true><<<dim3(8192), 256, 0, stream>>>(b3, l2g, l2b, d_out, flag);
}